// Round 11
// baseline (342.550 us; speedup 1.0000x reference)
//
#include <hip/hip_runtime.h>

#define NN 4096
#define EE 262144
#define INF_ 64
#define HH 128
#define HEADS 4
#define DH 32
#define LL 2
#define NH (NN * HH)
#define KSPLIT 8
#define L2E 1.4426950408889634f
#define GM ((NN / 128) * HEADS * KSPLIT)   // 1024 MHA blocks

typedef unsigned short u16;
typedef unsigned int u32;
using bf16x8 = __attribute__((ext_vector_type(8))) short;
using f32x4 = __attribute__((ext_vector_type(4))) float;

__device__ __forceinline__ float bf2f(u16 v) { return __uint_as_float(((u32)v) << 16); }
__device__ __forceinline__ u16 f2bf(float f) {
    u32 u = __float_as_uint(f);
    u32 r = (u + 0x7fffu + ((u >> 16) & 1u)) >> 16;
    return (u16)r;
}
__device__ __forceinline__ u32 encf(float f) {
    u32 b = __float_as_uint(f);
    return (b & 0x80000000u) ? ~b : (b | 0x80000000u);
}
__device__ __forceinline__ float decf(u32 u) {
    u32 b = (u & 0x80000000u) ? (u & 0x7fffffffu) : ~u;
    return __uint_as_float(b);
}

// ---------------- dtype detect + zero-init ----------------
__global__ __launch_bounds__(256) void k_detect(const u16* __restrict__ x, int* __restrict__ flag,
                                                int* __restrict__ cnt, u32* __restrict__ gmax) {
    int t = threadIdx.x;
    for (int i = t; i < NN; i += 256) cnt[i] = 0;
    if (t < 16) gmax[t] = 0;
    __shared__ int cs[256];
    u16 v = x[2 * t];
    int e = (v >> 7) & 0xFF;
    cs[t] = (e >= 100 && e <= 140) ? 1 : 0;
    __syncthreads();
    for (int s = 128; s > 0; s >>= 1) {
        if (t < s) cs[t] += cs[t + s];
        __syncthreads();
    }
    if (t == 0) *flag = (cs[0] >= 128) ? 1 : 0;
}

// ---------------- batched param conversion ----------------
#define MAXSEG 16
struct SegF { const void* src[MAXSEG]; int dst[MAXSEG]; int n[MAXSEG]; int cnt; };
__global__ void k_cvtf(SegF S, float* __restrict__ W, const int* __restrict__ flag) {
    int seg = blockIdx.y;
    if (seg >= S.cnt) return;
    int n = S.n[seg];
    float* d = W + S.dst[seg];
    const void* s = S.src[seg];
    int f = *flag;
    for (int i = blockIdx.x * 256 + threadIdx.x; i < n; i += gridDim.x * 256)
        d[i] = f ? bf2f(((const u16*)s)[i]) : ((const float*)s)[i];
}
struct SegB { const void* src[8]; u16* dst[8]; u16* dst2[8]; int n[8]; int cnt; };
__global__ void k_cvtb(SegB S, const int* __restrict__ flag) {
    int seg = blockIdx.y;
    if (seg >= S.cnt) return;
    int f = *flag;
    u16* d = S.dst[seg];
    u16* d2 = S.dst2[seg];
    if (f && !d2) return;
    int n = S.n[seg];
    const void* s = S.src[seg];
    for (int i = blockIdx.x * 256 + threadIdx.x; i < n; i += gridDim.x * 256) {
        if (d2) {
            float v = f ? bf2f(((const u16*)s)[i]) : ((const float*)s)[i];
            u16 h = f2bf(v);
            d[i] = h;
            d2[i] = f2bf(v - bf2f(h));
        } else {
            d[i] = f2bf(((const float*)s)[i]);
        }
    }
}

// ---------------- CSR build ----------------
__global__ void k_hist(const int* __restrict__ dst, int* __restrict__ cnt) {
    int e = blockIdx.x * blockDim.x + threadIdx.x;
    if (e < EE) atomicAdd(&cnt[dst[e]], 1);
}
__global__ __launch_bounds__(256) void k_scan(const int* __restrict__ cnt, int* __restrict__ rowstart,
                                              int* __restrict__ cursor) {
    __shared__ int part[256];
    int t = threadIdx.x;
    int loc[16];
    int s = 0;
#pragma unroll
    for (int i = 0; i < 16; ++i) { loc[i] = s; s += cnt[t * 16 + i]; }
    part[t] = s;
    __syncthreads();
    for (int off = 1; off < 256; off <<= 1) {
        int v = part[t];
        int a = (t >= off) ? part[t - off] : 0;
        __syncthreads();
        part[t] = v + a;
        __syncthreads();
    }
    int base = (t == 0) ? 0 : part[t - 1];
#pragma unroll
    for (int i = 0; i < 16; ++i) {
        rowstart[t * 16 + i] = base + loc[i];
        cursor[t * 16 + i] = base + loc[i];
    }
}
__global__ void k_scatter(const int* __restrict__ src, const int* __restrict__ dst,
                          int* __restrict__ cursor, int* __restrict__ esrc) {
    int e = blockIdx.x * blockDim.x + threadIdx.x;
    if (e < EE) {
        int d = dst[e];
        int p = atomicAdd(&cursor[d], 1);
        esrc[p] = src[e];
    }
}

// ---------------- generic MFMA GEMM ----------------
__global__ __launch_bounds__(128) void k_mgemm(const u16* __restrict__ Ahi, const u16* __restrict__ Alo,
                                               const u16* __restrict__ Wc, const u16* __restrict__ Wd,
                                               const int* __restrict__ flag,
                                               const float* __restrict__ bias,
                                               float* __restrict__ outf, u16* __restrict__ outb16,
                                               u16* __restrict__ outhi, u16* __restrict__ outlo,
                                               int K, int J, int relu) {
    const u16* Wb = (*flag) ? Wd : Wc;
    int wave = threadIdx.x >> 6, lane = threadIdx.x & 63;
    int grp = lane >> 4, lcol = lane & 15;
    int m0 = blockIdx.x * 32 + wave * 16;
    int j0 = blockIdx.y * 64;
    f32x4 acc[4];
#pragma unroll
    for (int s = 0; s < 4; ++s) acc[s] = (f32x4){0.f, 0.f, 0.f, 0.f};
    const u16* ah = Ahi + (size_t)(m0 + lcol) * K + grp * 8;
    const u16* al = Alo + (size_t)(m0 + lcol) * K + grp * 8;
    const u16* wb = Wb + (size_t)(j0 + lcol) * K + grp * 8;
    for (int k = 0; k < K; k += 32) {
        bf16x8 va = *(const bf16x8*)(ah + k);
        bf16x8 vl = *(const bf16x8*)(al + k);
#pragma unroll
        for (int s = 0; s < 4; ++s) {
            bf16x8 vw = *(const bf16x8*)(wb + (size_t)s * 16 * K + k);
            acc[s] = __builtin_amdgcn_mfma_f32_16x16x32_bf16(va, vw, acc[s], 0, 0, 0);
            acc[s] = __builtin_amdgcn_mfma_f32_16x16x32_bf16(vl, vw, acc[s], 0, 0, 0);
        }
    }
#pragma unroll
    for (int s = 0; s < 4; ++s) {
        int col = j0 + s * 16 + lcol;
        float bs = bias ? bias[col] : 0.f;
#pragma unroll
        for (int r = 0; r < 4; ++r) {
            float v = acc[s][r] + bs;
            if (relu) v = fmaxf(v, 0.f);
            size_t idx = (size_t)(m0 + grp * 4 + r) * J + col;
            if (outf) outf[idx] = v;
            if (outb16) outb16[idx] = f2bf(v);
            if (outhi) {
                u16 hv = f2bf(v);
                outhi[idx] = hv;
                outlo[idx] = f2bf(v - bf2f(hv));
            }
        }
    }
}

// ---------------- fused GAT-xp + QKV GEMM ----------------
__global__ __launch_bounds__(128) void k_gemm_gq(const u16* __restrict__ Ahi, const u16* __restrict__ Alo,
                                                 const u16* __restrict__ wgatc, const u16* __restrict__ wgatd,
                                                 const u16* __restrict__ wqkvc, const u16* __restrict__ wqkvd,
                                                 const int* __restrict__ flag,
                                                 const float* __restrict__ bqkv,
                                                 u16* __restrict__ xpb, u16* __restrict__ qkvb) {
    int wave = threadIdx.x >> 6, lane = threadIdx.x & 63;
    int grp = lane >> 4, lcol = lane & 15;
    int m0 = blockIdx.x * 32 + wave * 16;
    int jb = blockIdx.y;
    int j0 = jb * 64;
    int f = *flag;
    const u16* wgat = f ? wgatd : wgatc;
    const u16* wqkv = f ? wqkvd : wqkvc;
    const u16* Wb = (jb < 2) ? (wgat + (size_t)j0 * HH) : (wqkv + (size_t)(j0 - 128) * HH);
    f32x4 acc[4];
#pragma unroll
    for (int s = 0; s < 4; ++s) acc[s] = (f32x4){0.f, 0.f, 0.f, 0.f};
    const u16* ah = Ahi + (size_t)(m0 + lcol) * HH + grp * 8;
    const u16* al = Alo + (size_t)(m0 + lcol) * HH + grp * 8;
    const u16* wb = Wb + (size_t)lcol * HH + grp * 8;
    for (int k = 0; k < HH; k += 32) {
        bf16x8 va = *(const bf16x8*)(ah + k);
        bf16x8 vl = *(const bf16x8*)(al + k);
#pragma unroll
        for (int s = 0; s < 4; ++s) {
            bf16x8 vw = *(const bf16x8*)(wb + (size_t)s * 16 * HH + k);
            acc[s] = __builtin_amdgcn_mfma_f32_16x16x32_bf16(va, vw, acc[s], 0, 0, 0);
            acc[s] = __builtin_amdgcn_mfma_f32_16x16x32_bf16(vl, vw, acc[s], 0, 0, 0);
        }
    }
    if (jb < 2) {
#pragma unroll
        for (int s = 0; s < 4; ++s) {
            int col = j0 + s * 16 + lcol;
#pragma unroll
            for (int r = 0; r < 4; ++r)
                xpb[(size_t)(m0 + grp * 4 + r) * HH + col] = f2bf(acc[s][r]);
        }
    } else {
#pragma unroll
        for (int s = 0; s < 4; ++s) {
            int colq = j0 - 128 + s * 16 + lcol;
            float bs = bqkv[colq];
#pragma unroll
            for (int r = 0; r < 4; ++r)
                qkvb[(size_t)(m0 + grp * 4 + r) * 384 + colq] = f2bf(acc[s][r] + bs);
        }
    }
}

// ---------------- attlog (bf16 xp) + per-head global-max atomics ----------------
__global__ __launch_bounds__(256) void k_attlog(const u16* __restrict__ xpb, const float* __restrict__ asrc,
                                                const float* __restrict__ adst, float* __restrict__ als,
                                                float* __restrict__ ald, u32* __restrict__ gmax) {
    int t = blockIdx.x * 256 + threadIdx.x;
    int n = t >> 2, hh = t & 3;
    const u16* xr = xpb + (size_t)n * HH + hh * DH;
    float s1 = 0.f, s2 = 0.f;
#pragma unroll
    for (int d = 0; d < DH; ++d) {
        float v = bf2f(xr[d]);
        s1 += v * asrc[hh * DH + d];
        s2 += v * adst[hh * DH + d];
    }
    als[t] = s1;
    ald[t] = s2;
    __shared__ float red[256];
    int lt = threadIdx.x;
    red[lt] = s1;
    __syncthreads();
    for (int off = 128; off >= 4; off >>= 1) {
        if (lt < off) red[lt] = fmaxf(red[lt], red[lt + off]);
        __syncthreads();
    }
    if (lt < 4) atomicMax(&gmax[lt], encf(red[lt]));
    __syncthreads();
    red[lt] = s2;
    __syncthreads();
    for (int off = 128; off >= 4; off >>= 1) {
        if (lt < off) red[lt] = fmaxf(red[lt], red[lt + off]);
        __syncthreads();
    }
    if (lt < 4) atomicMax(&gmax[4 + lt], encf(red[lt]));
}

// ---------------- w_o GEMM + combine fused epilogue ----------------
__global__ __launch_bounds__(128) void k_gemm_wo(const u16* __restrict__ Ahi, const u16* __restrict__ Alo,
                                                 const u16* __restrict__ Wc, const u16* __restrict__ Wd,
                                                 const int* __restrict__ flag,
                                                 const float* __restrict__ bias,
                                                 const float* __restrict__ gatb, const float* __restrict__ hbuf,
                                                 const float* __restrict__ bgat, const float* __restrict__ gam,
                                                 const float* __restrict__ bet,
                                                 float* __restrict__ outb, u16* __restrict__ ohi,
                                                 u16* __restrict__ olo) {
    const u16* Wb = (*flag) ? Wd : Wc;
    int wave = threadIdx.x >> 6, lane = threadIdx.x & 63;
    int grp = lane >> 4, lcol = lane & 15;
    int m0 = blockIdx.x * 32 + wave * 16;
    int j0 = blockIdx.y * 64;
    f32x4 acc[4];
#pragma unroll
    for (int s = 0; s < 4; ++s) acc[s] = (f32x4){0.f, 0.f, 0.f, 0.f};
    const u16* ah = Ahi + (size_t)(m0 + lcol) * HH + grp * 8;
    const u16* al = Alo + (size_t)(m0 + lcol) * HH + grp * 8;
    const u16* wb = Wb + (size_t)(j0 + lcol) * HH + grp * 8;
    for (int k = 0; k < HH; k += 32) {
        bf16x8 va = *(const bf16x8*)(ah + k);
        bf16x8 vl = *(const bf16x8*)(al + k);
#pragma unroll
        for (int s = 0; s < 4; ++s) {
            bf16x8 vw = *(const bf16x8*)(wb + (size_t)s * 16 * HH + k);
            acc[s] = __builtin_amdgcn_mfma_f32_16x16x32_bf16(va, vw, acc[s], 0, 0, 0);
            acc[s] = __builtin_amdgcn_mfma_f32_16x16x32_bf16(vl, vw, acc[s], 0, 0, 0);
        }
    }
    float rs = rsqrtf(1.00001f);
#pragma unroll
    for (int s = 0; s < 4; ++s) {
        int col = j0 + s * 16 + lcol;
        float bs = bias[col];
        float g0 = gam[col] * rs, b0 = bet[col];
        float g1 = gam[HH + col] * rs, b1 = bet[HH + col];
        float bg = bgat[col];
#pragma unroll
        for (int r = 0; r < 4; ++r) {
            size_t idx = (size_t)(m0 + grp * 4 + r) * HH + col;
            float proj = acc[s][r] + bs;
            float hv = hbuf[idx];
            float hl = g0 * (gatb[idx] + bg + hv) + b0;
            float ha = g1 * (proj + hv) + b1;
            float v = hl + ha;
            outb[idx] = v;
            u16 hb = f2bf(v);
            ohi[idx] = hb;
            olo[idx] = f2bf(v - bf2f(hb));
        }
    }
}

// ---------------- w2 GEMM + final fused epilogue ----------------
__global__ __launch_bounds__(128) void k_gemm_w2(const u16* __restrict__ Ahi, const u16* __restrict__ Alo,
                                                 const u16* __restrict__ Wc, const u16* __restrict__ Wd,
                                                 const int* __restrict__ flag,
                                                 const float* __restrict__ bias,
                                                 const float* __restrict__ outb, const float* __restrict__ gam2,
                                                 const float* __restrict__ bet2,
                                                 float* __restrict__ hbuf, u16* __restrict__ hhi,
                                                 u16* __restrict__ hlo) {
    const u16* Wb = (*flag) ? Wd : Wc;
    int wave = threadIdx.x >> 6, lane = threadIdx.x & 63;
    int grp = lane >> 4, lcol = lane & 15;
    int m0 = blockIdx.x * 32 + wave * 16;
    int j0 = blockIdx.y * 64;
    const int K = 2 * HH;
    f32x4 acc[4];
#pragma unroll
    for (int s = 0; s < 4; ++s) acc[s] = (f32x4){0.f, 0.f, 0.f, 0.f};
    const u16* ah = Ahi + (size_t)(m0 + lcol) * K + grp * 8;
    const u16* al = Alo + (size_t)(m0 + lcol) * K + grp * 8;
    const u16* wb = Wb + (size_t)(j0 + lcol) * K + grp * 8;
    for (int k = 0; k < K; k += 32) {
        bf16x8 va = *(const bf16x8*)(ah + k);
        bf16x8 vl = *(const bf16x8*)(al + k);
#pragma unroll
        for (int s = 0; s < 4; ++s) {
            bf16x8 vw = *(const bf16x8*)(wb + (size_t)s * 16 * K + k);
            acc[s] = __builtin_amdgcn_mfma_f32_16x16x32_bf16(va, vw, acc[s], 0, 0, 0);
            acc[s] = __builtin_amdgcn_mfma_f32_16x16x32_bf16(vl, vw, acc[s], 0, 0, 0);
        }
    }
    float rs = rsqrtf(1.00001f);
#pragma unroll
    for (int s = 0; s < 4; ++s) {
        int col = j0 + s * 16 + lcol;
        float bs = bias[col];
        float g2 = gam2[col] * rs, b2 = bet2[col];
#pragma unroll
        for (int r = 0; r < 4; ++r) {
            size_t idx = (size_t)(m0 + grp * 4 + r) * HH + col;
            float mlpo = acc[s][r] + bs;
            float o2 = g2 * (outb[idx] + mlpo) + b2;
            float v = fmaxf(o2 + hbuf[idx], 0.f);
            hbuf[idx] = v;
            u16 hb = f2bf(v);
            hhi[idx] = hb;
            hlo[idx] = f2bf(v - bf2f(hb));
        }
    }
}

// ---------------- FAT kernel: MHA flash v5 (blocks < GM) + GAT (blocks >= GM) ----------------
#define GCHUNK 256
struct SmemMha {
    u16 K[64][40];
    u32 V[32][36];
    u16 P[4][32][66];
};
struct SmemGat {
    float red4[4 * 256];
    float accl[256];
    float elds[GCHUNK * 4];
    int slds[GCHUNK];
};
union SmemU {
    SmemMha m;
    SmemGat g;
};

__global__ __launch_bounds__(256) void k_gat_mha(const u16* __restrict__ qkvb,
                                                 float* __restrict__ PM, float* __restrict__ PL,
                                                 u16* __restrict__ PO,
                                                 const int* __restrict__ esrc, const int* __restrict__ rowstart,
                                                 const int* __restrict__ cnt, const float* __restrict__ als,
                                                 const float* __restrict__ ald, const u16* __restrict__ xpb,
                                                 float* __restrict__ gatout, const u32* __restrict__ gmax) {
    __shared__ __align__(16) SmemU S;
    int tid = threadIdx.x;
    if (blockIdx.x < GM) {
        // ===================== MHA v5 =====================
        const float C1 = 0.17677669529663687f * L2E;
        int head = blockIdx.x & 3;
        int qt = (blockIdx.x >> 2) & 31;
        int ks = blockIdx.x >> 7;
        int wave = tid >> 6, lane = tid & 63;
        int grp = lane >> 4, lcol = lane & 15;

        int qrow0 = qt * 128 + wave * 32;
        bf16x8 aQ0 = *(const bf16x8*)(qkvb + (size_t)(qrow0 + lcol) * 384 + head * 32 + grp * 8);
        bf16x8 aQ1 = *(const bf16x8*)(qkvb + (size_t)(qrow0 + 16 + lcol) * 384 + head * 32 + grp * 8);

        short onev = (lcol == 0) ? (short)0x3F80 : (short)0;
        bf16x8 bOne = {onev, onev, onev, onev, onev, onev, onev, onev};

        f32x4 oc00 = {0.f, 0.f, 0.f, 0.f}, oc01 = {0.f, 0.f, 0.f, 0.f};
        f32x4 oc10 = {0.f, 0.f, 0.f, 0.f}, oc11 = {0.f, 0.f, 0.f, 0.f};
        f32x4 ol0 = {0.f, 0.f, 0.f, 0.f}, ol1 = {0.f, 0.f, 0.f, 0.f};
        float msh = -INFINITY;

        int isK = (tid < 128);
        int st = tid & 127;
        int skey = st >> 1, shalf = (st & 1) * 16;
        int vj = st & 31, dgrp = st >> 5;
        int vkey0 = 32 * (vj & 1) + (vj >> 1);
        const u16* kptr = qkvb + 128 + head * 32 + shalf;
        const u16* vptr = qkvb + 256 + head * 32 + dgrp * 8;

        int kt0 = ks * (NN / KSPLIT);
        bf16x8 r0, r1;
        if (isK) {
            r0 = *(const bf16x8*)(kptr + (size_t)(kt0 + skey) * 384);
            r1 = *(const bf16x8*)(kptr + (size_t)(kt0 + skey) * 384 + 8);
        } else {
            r0 = *(const bf16x8*)(vptr + (size_t)(kt0 + vkey0) * 384);
            r1 = *(const bf16x8*)(vptr + (size_t)(kt0 + vkey0 + 16) * 384);
        }

        const int NT = (NN / KSPLIT) / 64;
        for (int t = 0; t < NT; ++t) {
            if (isK) {
                *(bf16x8*)(&S.m.K[skey][shalf]) = r0;
                *(bf16x8*)(&S.m.K[skey][shalf + 8]) = r1;
            } else {
#pragma unroll
                for (int j = 0; j < 8; ++j)
                    S.m.V[dgrp * 8 + j][vj] = (u32)(u16)r0[j] | ((u32)(u16)r1[j] << 16);
            }
            __syncthreads();
            if (t + 1 < NT) {
                int kn = kt0 + (t + 1) * 64;
                if (isK) {
                    r0 = *(const bf16x8*)(kptr + (size_t)(kn + skey) * 384);
                    r1 = *(const bf16x8*)(kptr + (size_t)(kn + skey) * 384 + 8);
                } else {
                    r0 = *(const bf16x8*)(vptr + (size_t)(kn + vkey0) * 384);
                    r1 = *(const bf16x8*)(vptr + (size_t)(kn + vkey0 + 16) * 384);
                }
            }
            f32x4 sc0[4], sc1[4];
            f32x4 zero = {0.f, 0.f, 0.f, 0.f};
#pragma unroll
            for (int s = 0; s < 4; ++s) {
                bf16x8 bK = *(const bf16x8*)(&S.m.K[s * 16 + lcol][grp * 8]);
                sc0[s] = __builtin_amdgcn_mfma_f32_16x16x32_bf16(aQ0, bK, zero, 0, 0, 0);
                sc1[s] = __builtin_amdgcn_mfma_f32_16x16x32_bf16(aQ1, bK, zero, 0, 0, 0);
            }
            float mymax = sc0[0][0];
#pragma unroll
            for (int s = 0; s < 4; ++s)
#pragma unroll
                for (int r = 0; r < 4; ++r) {
                    mymax = fmaxf(mymax, sc0[s][r]);
                    mymax = fmaxf(mymax, sc1[s][r]);
                }
            mymax = fmaxf(mymax, __shfl_xor(mymax, 1));
            mymax = fmaxf(mymax, __shfl_xor(mymax, 2));
            mymax = fmaxf(mymax, __shfl_xor(mymax, 4));
            mymax = fmaxf(mymax, __shfl_xor(mymax, 8));
            float mnew = fmaxf(msh, mymax * C1);
            float cc = __builtin_exp2f(msh - mnew);
            msh = mnew;
#pragma unroll
            for (int r = 0; r < 4; ++r) {
                float p0 = __builtin_exp2f(__builtin_fmaf(sc0[0][r], C1, -mnew));
                float p1 = __builtin_exp2f(__builtin_fmaf(sc0[1][r], C1, -mnew));
                float p2 = __builtin_exp2f(__builtin_fmaf(sc0[2][r], C1, -mnew));
                float p3 = __builtin_exp2f(__builtin_fmaf(sc0[3][r], C1, -mnew));
                u32 a01 = __builtin_amdgcn_perm(__float_as_uint(p1), __float_as_uint(p0), 0x07060302u);
                u32 a23 = __builtin_amdgcn_perm(__float_as_uint(p3), __float_as_uint(p2), 0x07060302u);
                *(uint2*)(&S.m.P[wave][grp * 4 + r][4 * lcol]) = make_uint2(a01, a23);
                float q0 = __builtin_exp2f(__builtin_fmaf(sc1[0][r], C1, -mnew));
                float q1 = __builtin_exp2f(__builtin_fmaf(sc1[1][r], C1, -mnew));
                float q2 = __builtin_exp2f(__builtin_fmaf(sc1[2][r], C1, -mnew));
                float q3 = __builtin_exp2f(__builtin_fmaf(sc1[3][r], C1, -mnew));
                u32 b01 = __builtin_amdgcn_perm(__float_as_uint(q1), __float_as_uint(q0), 0x07060302u);
                u32 b23 = __builtin_amdgcn_perm(__float_as_uint(q3), __float_as_uint(q2), 0x07060302u);
                *(uint2*)(&S.m.P[wave][16 + grp * 4 + r][4 * lcol]) = make_uint2(b01, b23);
            }
            oc00 *= cc; oc01 *= cc; ol0 *= cc;
            oc10 *= cc; oc11 *= cc; ol1 *= cc;
#pragma unroll
            for (int c2 = 0; c2 < 2; ++c2) {
                bf16x8 aP0 = *(const bf16x8*)(&S.m.P[wave][lcol][c2 * 32 + grp * 8]);
                bf16x8 aP1 = *(const bf16x8*)(&S.m.P[wave][16 + lcol][c2 * 32 + grp * 8]);
                bf16x8 bV0 = *(const bf16x8*)(&S.m.V[lcol][c2 * 16 + grp * 4]);
                bf16x8 bV1 = *(const bf16x8*)(&S.m.V[16 + lcol][c2 * 16 + grp * 4]);
                oc00 = __builtin_amdgcn_mfma_f32_16x16x32_bf16(aP0, bV0, oc00, 0, 0, 0);
                oc01 = __builtin_amdgcn_mfma_f32_16x16x32_bf16(aP0, bV1, oc01, 0, 0, 0);
                ol0 = __builtin_amdgcn_mfma_f32_16x16x32_bf16(aP0, bOne, ol0, 0, 0, 0);
                oc10 = __builtin_amdgcn_mfma_f32_16x16x32_bf16(aP1, bV0, oc10, 0, 0, 0);
                oc11 = __builtin_amdgcn_mfma_f32_16x16x32_bf16(aP1, bV1, oc11, 0, 0, 0);
                ol1 = __builtin_amdgcn_mfma_f32_16x16x32_bf16(aP1, bOne, ol1, 0, 0, 0);
            }
            __syncthreads();
        }
#pragma unroll
        for (int r = 0; r < 4; ++r) {
            int row0 = qrow0 + grp * 4 + r;
            size_t b0 = ((size_t)row0 * HEADS + head) * KSPLIT + ks;
            PO[b0 * 32 + lcol] = f2bf(oc00[r]);
            PO[b0 * 32 + 16 + lcol] = f2bf(oc01[r]);
            int row1 = row0 + 16;
            size_t b1 = ((size_t)row1 * HEADS + head) * KSPLIT + ks;
            PO[b1 * 32 + lcol] = f2bf(oc10[r]);
            PO[b1 * 32 + 16 + lcol] = f2bf(oc11[r]);
            if (lcol == 0) {
                PM[b0] = msh;
                PL[b0] = ol0[r];
                PM[b1] = msh;
                PL[b1] = ol1[r];
            }
        }
    } else {
        // ===================== GAT (256 threads, 2-way edge split per dim) =====================
        int n = blockIdx.x - GM;
        int t = tid;
        int dim = t & 127, half = t >> 7;
        int base = rowstart[n], c = cnt[n];
        float4 adv = ((const float4*)ald)[n];
        float ad[4] = {adv.x, adv.y, adv.z, adv.w};
        float M2[4];
#pragma unroll
        for (int h = 0; h < 4; ++h) {
            float bound = decf(gmax[h]) + decf(gmax[4 + h]);
            float M = bound >= 0.f ? bound : 0.2f * bound;
            M2[h] = M * L2E;
        }
        float dsum[4] = {0.f, 0.f, 0.f, 0.f};
        float acc = 0.f;
        int ht = dim >> 5;
        for (int ch = 0; ch < c; ch += GCHUNK) {
            int cn = min(GCHUNK, c - ch);
            __syncthreads();
            for (int i = t; i < cn; i += 256) {
                int s = esrc[base + ch + i];
                S.g.slds[i] = s;
                float4 as = ((const float4*)als)[s];
                float lg, e;
                lg = as.x + ad[0]; lg = lg >= 0.f ? lg : 0.2f * lg; e = __builtin_exp2f(lg * L2E - M2[0]); S.g.elds[i * 4 + 0] = e; dsum[0] += e;
                lg = as.y + ad[1]; lg = lg >= 0.f ? lg : 0.2f * lg; e = __builtin_exp2f(lg * L2E - M2[1]); S.g.elds[i * 4 + 1] = e; dsum[1] += e;
                lg = as.z + ad[2]; lg = lg >= 0.f ? lg : 0.2f * lg; e = __builtin_exp2f(lg * L2E - M2[2]); S.g.elds[i * 4 + 2] = e; dsum[2] += e;
                lg = as.w + ad[3]; lg = lg >= 0.f ? lg : 0.2f * lg; e = __builtin_exp2f(lg * L2E - M2[3]); S.g.elds[i * 4 + 3] = e; dsum[3] += e;
            }
            __syncthreads();
            int i = half;
            for (; i + 6 < cn; i += 8) {
                int s0 = S.g.slds[i], s1 = S.g.slds[i + 2], s2 = S.g.slds[i + 4], s3 = S.g.slds[i + 6];
                float x0 = bf2f(xpb[(size_t)s0 * HH + dim]);
                float x1 = bf2f(xpb[(size_t)s1 * HH + dim]);
                float x2 = bf2f(xpb[(size_t)s2 * HH + dim]);
                float x3 = bf2f(xpb[(size_t)s3 * HH + dim]);
                acc += S.g.elds[i * 4 + ht] * x0 + S.g.elds[(i + 2) * 4 + ht] * x1;
                acc += S.g.elds[(i + 4) * 4 + ht] * x2 + S.g.elds[(i + 6) * 4 + ht] * x3;
            }
            for (; i < cn; i += 2)
                acc += S.g.elds[i * 4 + ht] * bf2f(xpb[(size_t)S.g.slds[i] * HH + dim]);
        }
        __syncthreads();
#pragma unroll
        for (int h = 0; h < 4; ++h) S.g.red4[h * 256 + t] = dsum[h];
        S.g.accl[t] = acc;
        __syncthreads();
        for (int s2 = 128; s2 > 0; s2 >>= 1) {
            if (t < s2) {
#pragma unroll
                for (int h = 0; h < 4; ++h)
                    S.g.red4[h * 256 + t] += S.g.red4[h * 256 + t + s2];
            }
            __syncthreads();
        }
        if (t < 128) {
            float inv = 1.f / (S.g.red4[ht * 256] + 1e-16f);
            gatout[(size_t)n * HH + t] = (S.g.accl[t] + S.g.accl[t + 128]) * inv;
        }
    }
}

__global__ void k_mha_comb(const float* __restrict__ PM, const float* __restrict__ PL,
                           const u16* __restrict__ PO, u16* __restrict__ atthi,
                           u16* __restrict__ attlo) {
    int t = blockIdx.x * 256 + threadIdx.x;
    if (t >= NN * HH) return;
    int row = t >> 7, col = t & 127;
    int head = col >> 5, dim = col & 31;
    size_t b0 = ((size_t)row * HEADS + head) * KSPLIT;
    float m = -INFINITY;
#pragma unroll
    for (int k = 0; k < KSPLIT; ++k) m = fmaxf(m, PM[b0 + k]);
    float l = 0.f, o = 0.f;
#pragma unroll
    for (int k = 0; k < KSPLIT; ++k) {
        float w = __builtin_exp2f(PM[b0 + k] - m);
        l += PL[b0 + k] * w;
        o += bf2f(PO[(b0 + k) * 32 + dim]) * w;
    }
    float v = o / l;
    u16 h = f2bf(v);
    atthi[t] = h;
    attlo[t] = f2bf(v - bf2f(h));
}

// ---------------- output projection ----------------
__global__ __launch_bounds__(64) void k_out(const float* __restrict__ h, const float* __restrict__ w,
                                            const float* __restrict__ b, void* __restrict__ yout,
                                            const int* __restrict__ flag) {
    int n = blockIdx.x, l = threadIdx.x;
    float a0 = 0.f, a1 = 0.f;
    for (int k = l; k < HH; k += 64) {
        float hv = h[(size_t)n * HH + k];
        a0 += hv * w[k];
        a1 += hv * w[HH + k];
    }
#pragma unroll
    for (int off = 32; off > 0; off >>= 1) {
        a0 += __shfl_xor(a0, off);
        a1 += __shfl_xor(a1, off);
    }
    if (l == 0) {
        float o0 = a0 + b[0], o1 = a1 + b[1];
        if (*flag) {
            u16* y = (u16*)yout;
            y[n * 2 + 0] = f2bf(o0);
            y[n * 2 + 1] = f2bf(o1);
        } else {
            float* y = (float*)yout;
            y[n * 2 + 0] = o0;
            y[n * 2 + 1] = o1;
        }
    }
}

extern "C" void kernel_launch(void* const* d_in, const int* in_sizes, int n_in,
                              void* d_out, int out_size, void* d_ws, size_t ws_size,
                              hipStream_t stream) {
    float* W = (float*)d_ws;
    size_t o = 0;
    auto take = [&](size_t n) { size_t r = o; o += n; return r; };
    size_t pb_in = take(HH);
    size_t pattS = take(LL * HEADS * DH);
    size_t pattD = take(LL * HEADS * DH);
    size_t pb_gat = take(LL * HH);
    size_t pb_qkv = take(LL * 3 * HH);
    size_t pb_o  = take(LL * HH);
    size_t pbn_g = take(LL * 3 * HH);
    size_t pbn_b = take(LL * 3 * HH);
    size_t pb1   = take(LL * 2 * HH);
    size_t pb2   = take(LL * HH);
    size_t pw_out = take(2 * HH);
    size_t pb_out = take(2);
    auto takeb = [&](size_t nu16) { size_t r = o; o += (nu16 + 1) / 2; return r; };
    size_t bw_in  = takeb(HH * INF_);
    size_t bw_gat = takeb(LL * HH * HH);
    size_t bw_qkv = takeb(LL * 3 * HH * HH);
    size_t bw_o   = takeb(LL * HH * HH);
    size_t bw1    = takeb(LL * 2 * HH * HH);
    size_t bw2    = takeb(LL * HH * 2 * HH);
    o = (o + 127) & ~(size_t)127;
    size_t ohbuf = take(NH);
    size_t ogat  = take(NH);
    size_t otmp  = take(NH);
    size_t oals  = take(NN * HEADS);
    size_t oald  = take(NN * HEADS);
    size_t opm   = take(NN * HEADS * KSPLIT);
    size_t opl   = take(NN * HEADS * KSPLIT);
    size_t opo   = takeb((size_t)NN * HEADS * KSPLIT * 32);
    size_t oqkvb = takeb(NN * 384);
    size_t oxpb  = takeb(NH);
    size_t oxhi  = takeb(NN * INF_);
    size_t oxlo  = takeb(NN * INF_);
    size_t ohhi  = takeb(NH);
    size_t ohlo  = takeb(NH);
    size_t oahi  = takeb(NH);
    size_t oalo  = takeb(NH);
    size_t oohi  = takeb(NH);
    size_t oolo  = takeb(NH);
    size_t omhi  = takeb(NN * 2 * HH);
    size_t omlo  = takeb(NN * 2 * HH);
    int* ibase    = (int*)(W + o);
    int* iflag    = ibase;
    int* cnt      = ibase + 64;
    int* rowstart = cnt + NN;
    int* cursor   = rowstart + NN;
    int* esrc     = cursor + NN;
    u32* gmax     = (u32*)(esrc + EE);

    float* hbuf = W + ohbuf;
    float* gatb = W + ogat;
    float* tmp  = W + otmp;
    float* als  = W + oals;
    float* ald  = W + oald;
    float* pmb  = W + opm;
    float* plb  = W + opl;
    u16* pob  = (u16*)(W + opo);
    u16* qkvb = (u16*)(W + oqkvb);
    u16* xpb  = (u16*)(W + oxpb);
    u16* xhi = (u16*)(W + oxhi), *xlo = (u16*)(W + oxlo);
    u16* hhi = (u16*)(W + ohhi), *hlo = (u16*)(W + ohlo);
    u16* ahi = (u16*)(W + oahi), *alo = (u16*)(W + oalo);
    u16* ohi = (u16*)(W + oohi), *olo = (u16*)(W + oolo);
    u16* mhi = (u16*)(W + omhi), *mlo = (u16*)(W + omlo);

    const int* src = (const int*)d_in[1];
    const int* dst = (const int*)d_in[1] + EE;
    const u16* dw_in  = (const u16*)d_in[2];
    const u16* dw_gat = (const u16*)d_in[4];
    const u16* dw_qkv = (const u16*)d_in[8];
    const u16* dw_o   = (const u16*)d_in[10];
    const u16* dw1    = (const u16*)d_in[14];
    const u16* dw2    = (const u16*)d_in[16];

    k_detect<<<1, 256, 0, stream>>>((const u16*)d_in[0], iflag, cnt, gmax);

    SegF SF = {};
    int nf = 0;
    auto addf = [&](int idx, size_t off, int n) { SF.src[nf] = d_in[idx]; SF.dst[nf] = (int)off; SF.n[nf] = n; ++nf; };
    addf(3, pb_in, HH);
    addf(5, pattS, LL * HEADS * DH);
    addf(6, pattD, LL * HEADS * DH);
    addf(7, pb_gat, LL * HH);
    addf(9, pb_qkv, LL * 3 * HH);
    addf(11, pb_o, LL * HH);
    addf(12, pbn_g, LL * 3 * HH);
    addf(13, pbn_b, LL * 3 * HH);
    addf(15, pb1, LL * 2 * HH);
    addf(17, pb2, LL * HH);
    addf(18, pw_out, 2 * HH);
    addf(19, pb_out, 2);
    SF.cnt = nf;
    k_cvtf<<<dim3(8, nf), 256, 0, stream>>>(SF, W, iflag);

    SegB SB = {};
    int nb = 0;
    auto addb = [&](int idx, size_t off, int n, u16* d2) {
        SB.src[nb] = d_in[idx]; SB.dst[nb] = (u16*)(W + off); SB.dst2[nb] = d2; SB.n[nb] = n; ++nb;
    };
    addb(2, bw_in, HH * INF_, nullptr);
    addb(4, bw_gat, LL * HH * HH, nullptr);
    addb(8, bw_qkv, LL * 3 * HH * HH, nullptr);
    addb(10, bw_o, LL * HH * HH, nullptr);
    addb(14, bw1, LL * 2 * HH * HH, nullptr);
    addb(16, bw2, LL * HH * 2 * HH, nullptr);
    SB.src[nb] = d_in[0]; SB.dst[nb] = xhi; SB.dst2[nb] = xlo; SB.n[nb] = NN * INF_; ++nb;
    SB.cnt = nb;
    k_cvtb<<<dim3(128, nb), 256, 0, stream>>>(SB, iflag);

    k_hist<<<EE / 256, 256, 0, stream>>>(dst, cnt);
    k_scan<<<1, 256, 0, stream>>>(cnt, rowstart, cursor);
    k_scatter<<<EE / 256, 256, 0, stream>>>(src, dst, cursor, esrc);

    k_mgemm<<<dim3(NN / 32, HH / 64), 128, 0, stream>>>(xhi, xlo, (u16*)(W + bw_in), dw_in, iflag,
                                                        W + pb_in, hbuf, nullptr, hhi, hlo, INF_, HH, 1);

    for (int l = 0; l < LL; ++l) {
        k_gemm_gq<<<dim3(NN / 32, 8), 128, 0, stream>>>(hhi, hlo,
                                                        (u16*)(W + bw_gat) + (size_t)l * HH * HH,
                                                        dw_gat + (size_t)l * HH * HH,
                                                        (u16*)(W + bw_qkv) + (size_t)l * 3 * HH * HH,
                                                        dw_qkv + (size_t)l * 3 * HH * HH,
                                                        iflag, W + pb_qkv + l * 3 * HH, xpb, qkvb);
        k_attlog<<<(NN * HEADS) / 256, 256, 0, stream>>>(xpb, W + pattS + l * HEADS * DH,
                                                         W + pattD + l * HEADS * DH, als, ald,
                                                         gmax + l * 8);
        // fused MHA-split + GAT aggregation (independent branches, one launch)
        k_gat_mha<<<GM + NN, 256, 0, stream>>>(qkvb, pmb, plb, pob,
                                               esrc, rowstart, cnt, als, ald, xpb, gatb, gmax + l * 8);
        k_mha_comb<<<(NN * HH) / 256, 256, 0, stream>>>(pmb, plb, pob, ahi, alo);
        k_gemm_wo<<<dim3(NN / 32, HH / 64), 128, 0, stream>>>(ahi, alo,
                                                              (u16*)(W + bw_o) + (size_t)l * HH * HH,
                                                              dw_o + (size_t)l * HH * HH, iflag,
                                                              W + pb_o + l * HH, gatb, hbuf,
                                                              W + pb_gat + l * HH, W + pbn_g + l * 3 * HH,
                                                              W + pbn_b + l * 3 * HH, tmp, ohi, olo);
        k_mgemm<<<dim3(NN / 32, 256 / 64), 128, 0, stream>>>(ohi, olo,
                                                             (u16*)(W + bw1) + (size_t)l * 2 * HH * HH,
                                                             dw1 + (size_t)l * 2 * HH * HH, iflag,
                                                             W + pb1 + l * 2 * HH, nullptr, nullptr,
                                                             mhi, mlo, HH, 2 * HH, 1);
        k_gemm_w2<<<dim3(NN / 32, HH / 64), 128, 0, stream>>>(mhi, mlo,
                                                              (u16*)(W + bw2) + (size_t)l * HH * 2 * HH,
                                                              dw2 + (size_t)l * HH * 2 * HH, iflag,
                                                              W + pb2 + l * HH, tmp,
                                                              W + pbn_g + l * 3 * HH + 2 * HH,
                                                              W + pbn_b + l * 3 * HH + 2 * HH,
                                                              hbuf, hhi, hlo);
    }
    k_out<<<NN, 64, 0, stream>>>(hbuf, W + pw_out, W + pb_out, d_out, iflag);
}

// Round 12
// 324.998 us; speedup vs baseline: 1.0540x; 1.0540x over previous
//
#include <hip/hip_runtime.h>

#define NN 4096
#define EE 262144
#define INF_ 64
#define HH 128
#define HEADS 4
#define DH 32
#define LL 2
#define NH (NN * HH)
#define KSPLIT 16
#define L2E 1.4426950408889634f

typedef unsigned short u16;
typedef unsigned int u32;
using bf16x8 = __attribute__((ext_vector_type(8))) short;
using f32x4 = __attribute__((ext_vector_type(4))) float;

__device__ __forceinline__ float bf2f(u16 v) { return __uint_as_float(((u32)v) << 16); }
__device__ __forceinline__ u16 f2bf(float f) {
    u32 u = __float_as_uint(f);
    u32 r = (u + 0x7fffu + ((u >> 16) & 1u)) >> 16;
    return (u16)r;
}
__device__ __forceinline__ u32 encf(float f) {
    u32 b = __float_as_uint(f);
    return (b & 0x80000000u) ? ~b : (b | 0x80000000u);
}
__device__ __forceinline__ float decf(u32 u) {
    u32 b = (u & 0x80000000u) ? (u & 0x7fffffffu) : ~u;
    return __uint_as_float(b);
}

// ---------------- dtype detect + zero-init (cnt, gmax) ----------------
__global__ __launch_bounds__(256) void k_detect(const u16* __restrict__ x, int* __restrict__ flag,
                                                int* __restrict__ cnt, u32* __restrict__ gmax) {
    int t = threadIdx.x;
    for (int i = t; i < NN; i += 256) cnt[i] = 0;
    if (t < 16) gmax[t] = 0;
    __shared__ int cs[256];
    u16 v = x[2 * t];
    int e = (v >> 7) & 0xFF;
    cs[t] = (e >= 100 && e <= 140) ? 1 : 0;
    __syncthreads();
    for (int s = 128; s > 0; s >>= 1) {
        if (t < s) cs[t] += cs[t + s];
        __syncthreads();
    }
    if (t == 0) *flag = (cs[0] >= 128) ? 1 : 0;
}

// ---------------- batched param conversion ----------------
#define MAXSEG 16
struct SegF { const void* src[MAXSEG]; int dst[MAXSEG]; int n[MAXSEG]; int cnt; };
__global__ void k_cvtf(SegF S, float* __restrict__ W, const int* __restrict__ flag) {
    int seg = blockIdx.y;
    if (seg >= S.cnt) return;
    int n = S.n[seg];
    float* d = W + S.dst[seg];
    const void* s = S.src[seg];
    int f = *flag;
    for (int i = blockIdx.x * 256 + threadIdx.x; i < n; i += gridDim.x * 256)
        d[i] = f ? bf2f(((const u16*)s)[i]) : ((const float*)s)[i];
}
struct SegB { const void* src[8]; u16* dst[8]; u16* dst2[8]; int n[8]; int cnt; };
__global__ void k_cvtb(SegB S, const int* __restrict__ flag) {
    int seg = blockIdx.y;
    if (seg >= S.cnt) return;
    int f = *flag;
    u16* d = S.dst[seg];
    u16* d2 = S.dst2[seg];
    if (f && !d2) return;   // weights already bf16 in d_in
    int n = S.n[seg];
    const void* s = S.src[seg];
    for (int i = blockIdx.x * 256 + threadIdx.x; i < n; i += gridDim.x * 256) {
        if (d2) {
            float v = f ? bf2f(((const u16*)s)[i]) : ((const float*)s)[i];
            u16 h = f2bf(v);
            d[i] = h;
            d2[i] = f2bf(v - bf2f(h));
        } else {
            d[i] = f2bf(((const float*)s)[i]);
        }
    }
}

// ---------------- CSR build ----------------
__global__ void k_hist(const int* __restrict__ dst, int* __restrict__ cnt) {
    int e = blockIdx.x * blockDim.x + threadIdx.x;
    if (e < EE) atomicAdd(&cnt[dst[e]], 1);
}
__global__ __launch_bounds__(256) void k_scan(const int* __restrict__ cnt, int* __restrict__ rowstart,
                                              int* __restrict__ cursor) {
    __shared__ int part[256];
    int t = threadIdx.x;
    int loc[16];
    int s = 0;
#pragma unroll
    for (int i = 0; i < 16; ++i) { loc[i] = s; s += cnt[t * 16 + i]; }
    part[t] = s;
    __syncthreads();
    for (int off = 1; off < 256; off <<= 1) {
        int v = part[t];
        int a = (t >= off) ? part[t - off] : 0;
        __syncthreads();
        part[t] = v + a;
        __syncthreads();
    }
    int base = (t == 0) ? 0 : part[t - 1];
#pragma unroll
    for (int i = 0; i < 16; ++i) {
        rowstart[t * 16 + i] = base + loc[i];
        cursor[t * 16 + i] = base + loc[i];
    }
}
__global__ void k_scatter(const int* __restrict__ src, const int* __restrict__ dst,
                          int* __restrict__ cursor, int* __restrict__ esrc) {
    int e = blockIdx.x * blockDim.x + threadIdx.x;
    if (e < EE) {
        int d = dst[e];
        int p = atomicAdd(&cursor[d], 1);
        esrc[p] = src[e];
    }
}

// ---------------- generic MFMA GEMM, M-tile 32, runtime weight select ----------------
__global__ __launch_bounds__(128) void k_mgemm(const u16* __restrict__ Ahi, const u16* __restrict__ Alo,
                                               const u16* __restrict__ Wc, const u16* __restrict__ Wd,
                                               const int* __restrict__ flag,
                                               const float* __restrict__ bias,
                                               float* __restrict__ outf, u16* __restrict__ outb16,
                                               u16* __restrict__ outhi, u16* __restrict__ outlo,
                                               int K, int J, int relu) {
    const u16* Wb = (*flag) ? Wd : Wc;
    int wave = threadIdx.x >> 6, lane = threadIdx.x & 63;
    int grp = lane >> 4, lcol = lane & 15;
    int m0 = blockIdx.x * 32 + wave * 16;
    int j0 = blockIdx.y * 64;
    f32x4 acc[4];
#pragma unroll
    for (int s = 0; s < 4; ++s) acc[s] = (f32x4){0.f, 0.f, 0.f, 0.f};
    const u16* ah = Ahi + (size_t)(m0 + lcol) * K + grp * 8;
    const u16* al = Alo + (size_t)(m0 + lcol) * K + grp * 8;
    const u16* wb = Wb + (size_t)(j0 + lcol) * K + grp * 8;
    for (int k = 0; k < K; k += 32) {
        bf16x8 va = *(const bf16x8*)(ah + k);
        bf16x8 vl = *(const bf16x8*)(al + k);
#pragma unroll
        for (int s = 0; s < 4; ++s) {
            bf16x8 vw = *(const bf16x8*)(wb + (size_t)s * 16 * K + k);
            acc[s] = __builtin_amdgcn_mfma_f32_16x16x32_bf16(va, vw, acc[s], 0, 0, 0);
            acc[s] = __builtin_amdgcn_mfma_f32_16x16x32_bf16(vl, vw, acc[s], 0, 0, 0);
        }
    }
#pragma unroll
    for (int s = 0; s < 4; ++s) {
        int col = j0 + s * 16 + lcol;
        float bs = bias ? bias[col] : 0.f;
#pragma unroll
        for (int r = 0; r < 4; ++r) {
            float v = acc[s][r] + bs;
            if (relu) v = fmaxf(v, 0.f);
            size_t idx = (size_t)(m0 + grp * 4 + r) * J + col;
            if (outf) outf[idx] = v;
            if (outb16) outb16[idx] = f2bf(v);
            if (outhi) {
                u16 hv = f2bf(v);
                outhi[idx] = hv;
                outlo[idx] = f2bf(v - bf2f(hv));
            }
        }
    }
}

// ---------------- fused GAT-xp + QKV GEMM ----------------
__global__ __launch_bounds__(128) void k_gemm_gq(const u16* __restrict__ Ahi, const u16* __restrict__ Alo,
                                                 const u16* __restrict__ wgatc, const u16* __restrict__ wgatd,
                                                 const u16* __restrict__ wqkvc, const u16* __restrict__ wqkvd,
                                                 const int* __restrict__ flag,
                                                 const float* __restrict__ bqkv,
                                                 u16* __restrict__ xpb, u16* __restrict__ qkvb) {
    int wave = threadIdx.x >> 6, lane = threadIdx.x & 63;
    int grp = lane >> 4, lcol = lane & 15;
    int m0 = blockIdx.x * 32 + wave * 16;
    int jb = blockIdx.y;
    int j0 = jb * 64;
    int f = *flag;
    const u16* wgat = f ? wgatd : wgatc;
    const u16* wqkv = f ? wqkvd : wqkvc;
    const u16* Wb = (jb < 2) ? (wgat + (size_t)j0 * HH) : (wqkv + (size_t)(j0 - 128) * HH);
    f32x4 acc[4];
#pragma unroll
    for (int s = 0; s < 4; ++s) acc[s] = (f32x4){0.f, 0.f, 0.f, 0.f};
    const u16* ah = Ahi + (size_t)(m0 + lcol) * HH + grp * 8;
    const u16* al = Alo + (size_t)(m0 + lcol) * HH + grp * 8;
    const u16* wb = Wb + (size_t)lcol * HH + grp * 8;
    for (int k = 0; k < HH; k += 32) {
        bf16x8 va = *(const bf16x8*)(ah + k);
        bf16x8 vl = *(const bf16x8*)(al + k);
#pragma unroll
        for (int s = 0; s < 4; ++s) {
            bf16x8 vw = *(const bf16x8*)(wb + (size_t)s * 16 * HH + k);
            acc[s] = __builtin_amdgcn_mfma_f32_16x16x32_bf16(va, vw, acc[s], 0, 0, 0);
            acc[s] = __builtin_amdgcn_mfma_f32_16x16x32_bf16(vl, vw, acc[s], 0, 0, 0);
        }
    }
    if (jb < 2) {
#pragma unroll
        for (int s = 0; s < 4; ++s) {
            int col = j0 + s * 16 + lcol;
#pragma unroll
            for (int r = 0; r < 4; ++r)
                xpb[(size_t)(m0 + grp * 4 + r) * HH + col] = f2bf(acc[s][r]);
        }
    } else {
#pragma unroll
        for (int s = 0; s < 4; ++s) {
            int colq = j0 - 128 + s * 16 + lcol;
            float bs = bqkv[colq];
#pragma unroll
            for (int r = 0; r < 4; ++r)
                qkvb[(size_t)(m0 + grp * 4 + r) * 384 + colq] = f2bf(acc[s][r] + bs);
        }
    }
}

// ---------------- attlog (bf16 xp) + per-head global-max atomics ----------------
__global__ __launch_bounds__(256) void k_attlog(const u16* __restrict__ xpb, const float* __restrict__ asrc,
                                                const float* __restrict__ adst, float* __restrict__ als,
                                                float* __restrict__ ald, u32* __restrict__ gmax) {
    int t = blockIdx.x * 256 + threadIdx.x;
    int n = t >> 2, hh = t & 3;
    const u16* xr = xpb + (size_t)n * HH + hh * DH;
    float s1 = 0.f, s2 = 0.f;
#pragma unroll
    for (int d = 0; d < DH; ++d) {
        float v = bf2f(xr[d]);
        s1 += v * asrc[hh * DH + d];
        s2 += v * adst[hh * DH + d];
    }
    als[t] = s1;
    ald[t] = s2;
    __shared__ float red[256];
    int lt = threadIdx.x;
    red[lt] = s1;
    __syncthreads();
    for (int off = 128; off >= 4; off >>= 1) {
        if (lt < off) red[lt] = fmaxf(red[lt], red[lt + off]);
        __syncthreads();
    }
    if (lt < 4) atomicMax(&gmax[lt], encf(red[lt]));
    __syncthreads();
    red[lt] = s2;
    __syncthreads();
    for (int off = 128; off >= 4; off >>= 1) {
        if (lt < off) red[lt] = fmaxf(red[lt], red[lt + off]);
        __syncthreads();
    }
    if (lt < 4) atomicMax(&gmax[4 + lt], encf(red[lt]));
}

// ---------------- w_o GEMM + combine fused epilogue ----------------
__global__ __launch_bounds__(128) void k_gemm_wo(const u16* __restrict__ Ahi, const u16* __restrict__ Alo,
                                                 const u16* __restrict__ Wc, const u16* __restrict__ Wd,
                                                 const int* __restrict__ flag,
                                                 const float* __restrict__ bias,
                                                 const float* __restrict__ gatb, const float* __restrict__ hbuf,
                                                 const float* __restrict__ bgat, const float* __restrict__ gam,
                                                 const float* __restrict__ bet,
                                                 float* __restrict__ outb, u16* __restrict__ ohi,
                                                 u16* __restrict__ olo) {
    const u16* Wb = (*flag) ? Wd : Wc;
    int wave = threadIdx.x >> 6, lane = threadIdx.x & 63;
    int grp = lane >> 4, lcol = lane & 15;
    int m0 = blockIdx.x * 32 + wave * 16;
    int j0 = blockIdx.y * 64;
    f32x4 acc[4];
#pragma unroll
    for (int s = 0; s < 4; ++s) acc[s] = (f32x4){0.f, 0.f, 0.f, 0.f};
    const u16* ah = Ahi + (size_t)(m0 + lcol) * HH + grp * 8;
    const u16* al = Alo + (size_t)(m0 + lcol) * HH + grp * 8;
    const u16* wb = Wb + (size_t)(j0 + lcol) * HH + grp * 8;
    for (int k = 0; k < HH; k += 32) {
        bf16x8 va = *(const bf16x8*)(ah + k);
        bf16x8 vl = *(const bf16x8*)(al + k);
#pragma unroll
        for (int s = 0; s < 4; ++s) {
            bf16x8 vw = *(const bf16x8*)(wb + (size_t)s * 16 * HH + k);
            acc[s] = __builtin_amdgcn_mfma_f32_16x16x32_bf16(va, vw, acc[s], 0, 0, 0);
            acc[s] = __builtin_amdgcn_mfma_f32_16x16x32_bf16(vl, vw, acc[s], 0, 0, 0);
        }
    }
    float rs = rsqrtf(1.00001f);
#pragma unroll
    for (int s = 0; s < 4; ++s) {
        int col = j0 + s * 16 + lcol;
        float bs = bias[col];
        float g0 = gam[col] * rs, b0 = bet[col];
        float g1 = gam[HH + col] * rs, b1 = bet[HH + col];
        float bg = bgat[col];
#pragma unroll
        for (int r = 0; r < 4; ++r) {
            size_t idx = (size_t)(m0 + grp * 4 + r) * HH + col;
            float proj = acc[s][r] + bs;
            float hv = hbuf[idx];
            float hl = g0 * (gatb[idx] + bg + hv) + b0;
            float ha = g1 * (proj + hv) + b1;
            float v = hl + ha;
            outb[idx] = v;
            u16 hb = f2bf(v);
            ohi[idx] = hb;
            olo[idx] = f2bf(v - bf2f(hb));
        }
    }
}

// ---------------- w2 GEMM + final fused epilogue ----------------
__global__ __launch_bounds__(128) void k_gemm_w2(const u16* __restrict__ Ahi, const u16* __restrict__ Alo,
                                                 const u16* __restrict__ Wc, const u16* __restrict__ Wd,
                                                 const int* __restrict__ flag,
                                                 const float* __restrict__ bias,
                                                 const float* __restrict__ outb, const float* __restrict__ gam2,
                                                 const float* __restrict__ bet2,
                                                 float* __restrict__ hbuf, u16* __restrict__ hhi,
                                                 u16* __restrict__ hlo) {
    const u16* Wb = (*flag) ? Wd : Wc;
    int wave = threadIdx.x >> 6, lane = threadIdx.x & 63;
    int grp = lane >> 4, lcol = lane & 15;
    int m0 = blockIdx.x * 32 + wave * 16;
    int j0 = blockIdx.y * 64;
    const int K = 2 * HH;
    f32x4 acc[4];
#pragma unroll
    for (int s = 0; s < 4; ++s) acc[s] = (f32x4){0.f, 0.f, 0.f, 0.f};
    const u16* ah = Ahi + (size_t)(m0 + lcol) * K + grp * 8;
    const u16* al = Alo + (size_t)(m0 + lcol) * K + grp * 8;
    const u16* wb = Wb + (size_t)(j0 + lcol) * K + grp * 8;
    for (int k = 0; k < K; k += 32) {
        bf16x8 va = *(const bf16x8*)(ah + k);
        bf16x8 vl = *(const bf16x8*)(al + k);
#pragma unroll
        for (int s = 0; s < 4; ++s) {
            bf16x8 vw = *(const bf16x8*)(wb + (size_t)s * 16 * K + k);
            acc[s] = __builtin_amdgcn_mfma_f32_16x16x32_bf16(va, vw, acc[s], 0, 0, 0);
            acc[s] = __builtin_amdgcn_mfma_f32_16x16x32_bf16(vl, vw, acc[s], 0, 0, 0);
        }
    }
    float rs = rsqrtf(1.00001f);
#pragma unroll
    for (int s = 0; s < 4; ++s) {
        int col = j0 + s * 16 + lcol;
        float bs = bias[col];
        float g2 = gam2[col] * rs, b2 = bet2[col];
#pragma unroll
        for (int r = 0; r < 4; ++r) {
            size_t idx = (size_t)(m0 + grp * 4 + r) * HH + col;
            float mlpo = acc[s][r] + bs;
            float o2 = g2 * (outb[idx] + mlpo) + b2;
            float v = fmaxf(o2 + hbuf[idx], 0.f);
            hbuf[idx] = v;
            u16 hb = f2bf(v);
            hhi[idx] = hb;
            hlo[idx] = f2bf(v - bf2f(hb));
        }
    }
}

// ---------------- GAT: single fused pass with global-max bound ----------------
#define GCHUNK 256
__global__ __launch_bounds__(128) void k_gat_node(const int* __restrict__ esrc, const int* __restrict__ rowstart,
                                                  const int* __restrict__ cnt, const float* __restrict__ als,
                                                  const float* __restrict__ ald, const u16* __restrict__ xpb,
                                                  float* __restrict__ gatout, const u32* __restrict__ gmax) {
    int n = blockIdx.x, t = threadIdx.x;
    int base = rowstart[n], c = cnt[n];
    float4 adv = ((const float4*)ald)[n];
    float ad[4] = {adv.x, adv.y, adv.z, adv.w};
    float M2[4];
#pragma unroll
    for (int h = 0; h < 4; ++h) {
        float bound = decf(gmax[h]) + decf(gmax[4 + h]);
        float M = bound >= 0.f ? bound : 0.2f * bound;
        M2[h] = M * L2E;
    }
    __shared__ float red[512];
    __shared__ float elds[GCHUNK * 4];
    __shared__ int slds[GCHUNK];
    float dsum[4] = {0.f, 0.f, 0.f, 0.f};
    float acc = 0.f;
    int ht = t >> 5;
    for (int ch = 0; ch < c; ch += GCHUNK) {
        int cn = min(GCHUNK, c - ch);
        __syncthreads();
        for (int i = t; i < cn; i += 128) {
            int s = esrc[base + ch + i];
            slds[i] = s;
            float4 as = ((const float4*)als)[s];
            float lg, e;
            lg = as.x + ad[0]; lg = lg >= 0.f ? lg : 0.2f * lg; e = __builtin_exp2f(lg * L2E - M2[0]); elds[i * 4 + 0] = e; dsum[0] += e;
            lg = as.y + ad[1]; lg = lg >= 0.f ? lg : 0.2f * lg; e = __builtin_exp2f(lg * L2E - M2[1]); elds[i * 4 + 1] = e; dsum[1] += e;
            lg = as.z + ad[2]; lg = lg >= 0.f ? lg : 0.2f * lg; e = __builtin_exp2f(lg * L2E - M2[2]); elds[i * 4 + 2] = e; dsum[2] += e;
            lg = as.w + ad[3]; lg = lg >= 0.f ? lg : 0.2f * lg; e = __builtin_exp2f(lg * L2E - M2[3]); elds[i * 4 + 3] = e; dsum[3] += e;
        }
        __syncthreads();
        int i = 0;
        for (; i + 4 <= cn; i += 4) {
            int s0 = slds[i], s1 = slds[i + 1], s2 = slds[i + 2], s3 = slds[i + 3];
            float x0 = bf2f(xpb[(size_t)s0 * HH + t]);
            float x1 = bf2f(xpb[(size_t)s1 * HH + t]);
            float x2 = bf2f(xpb[(size_t)s2 * HH + t]);
            float x3 = bf2f(xpb[(size_t)s3 * HH + t]);
            acc += elds[i * 4 + ht] * x0 + elds[(i + 1) * 4 + ht] * x1;
            acc += elds[(i + 2) * 4 + ht] * x2 + elds[(i + 3) * 4 + ht] * x3;
        }
        for (; i < cn; ++i) acc += elds[i * 4 + ht] * bf2f(xpb[(size_t)slds[i] * HH + t]);
    }
    __syncthreads();
#pragma unroll
    for (int h = 0; h < 4; ++h) red[h * 128 + t] = dsum[h];
    __syncthreads();
    for (int s2 = 64; s2 > 0; s2 >>= 1) {
        if (t < s2) {
#pragma unroll
            for (int h = 0; h < 4; ++h)
                red[h * 128 + t] += red[h * 128 + t + s2];
        }
        __syncthreads();
    }
    float inv = 1.f / (red[ht * 128] + 1e-16f);
    gatout[(size_t)n * HH + t] = acc * inv;
}

// ---------------- MHA flash v5: 2 Q-frags/wave (128 rows/block), l-via-MFMA, KSPLIT=16 ----------------
__global__ __launch_bounds__(256) void k_mha_split(const u16* __restrict__ qkvb,
                                                   float* __restrict__ PM, float* __restrict__ PL,
                                                   u16* __restrict__ PO) {
    const float C1 = 0.17677669529663687f * L2E;
    int head = blockIdx.x & 3;
    int qt = (blockIdx.x >> 2) & 31;
    int ks = blockIdx.x >> 7;
    int tid = threadIdx.x;
    int wave = tid >> 6, lane = tid & 63;
    int grp = lane >> 4, lcol = lane & 15;

    __shared__ __align__(16) u16 Klds[64][40];
    __shared__ __align__(16) u32 Vlds[32][36];
    __shared__ __align__(16) u16 Plds[4][32][66];

    int qrow0 = qt * 128 + wave * 32;
    bf16x8 aQ0 = *(const bf16x8*)(qkvb + (size_t)(qrow0 + lcol) * 384 + head * 32 + grp * 8);
    bf16x8 aQ1 = *(const bf16x8*)(qkvb + (size_t)(qrow0 + 16 + lcol) * 384 + head * 32 + grp * 8);

    short onev = (lcol == 0) ? (short)0x3F80 : (short)0;
    bf16x8 bOne = {onev, onev, onev, onev, onev, onev, onev, onev};

    f32x4 oc00 = {0.f, 0.f, 0.f, 0.f}, oc01 = {0.f, 0.f, 0.f, 0.f};
    f32x4 oc10 = {0.f, 0.f, 0.f, 0.f}, oc11 = {0.f, 0.f, 0.f, 0.f};
    f32x4 ol0 = {0.f, 0.f, 0.f, 0.f}, ol1 = {0.f, 0.f, 0.f, 0.f};
    float msh = -INFINITY;

    int isK = (tid < 128);
    int st = tid & 127;
    int skey = st >> 1, shalf = (st & 1) * 16;
    int vj = st & 31, dgrp = st >> 5;
    int vkey0 = 32 * (vj & 1) + (vj >> 1);
    const u16* kptr = qkvb + 128 + head * 32 + shalf;
    const u16* vptr = qkvb + 256 + head * 32 + dgrp * 8;

    int kt0 = ks * (NN / KSPLIT);
    bf16x8 r0, r1;
    if (isK) {
        r0 = *(const bf16x8*)(kptr + (size_t)(kt0 + skey) * 384);
        r1 = *(const bf16x8*)(kptr + (size_t)(kt0 + skey) * 384 + 8);
    } else {
        r0 = *(const bf16x8*)(vptr + (size_t)(kt0 + vkey0) * 384);
        r1 = *(const bf16x8*)(vptr + (size_t)(kt0 + vkey0 + 16) * 384);
    }

    const int NT = (NN / KSPLIT) / 64;
    for (int t = 0; t < NT; ++t) {
        if (isK) {
            *(bf16x8*)(&Klds[skey][shalf]) = r0;
            *(bf16x8*)(&Klds[skey][shalf + 8]) = r1;
        } else {
#pragma unroll
            for (int j = 0; j < 8; ++j)
                Vlds[dgrp * 8 + j][vj] = (u32)(u16)r0[j] | ((u32)(u16)r1[j] << 16);
        }
        __syncthreads();
        if (t + 1 < NT) {
            int kn = kt0 + (t + 1) * 64;
            if (isK) {
                r0 = *(const bf16x8*)(kptr + (size_t)(kn + skey) * 384);
                r1 = *(const bf16x8*)(kptr + (size_t)(kn + skey) * 384 + 8);
            } else {
                r0 = *(const bf16x8*)(vptr + (size_t)(kn + vkey0) * 384);
                r1 = *(const bf16x8*)(vptr + (size_t)(kn + vkey0 + 16) * 384);
            }
        }
        f32x4 sc0[4], sc1[4];
        f32x4 zero = {0.f, 0.f, 0.f, 0.f};
#pragma unroll
        for (int s = 0; s < 4; ++s) {
            bf16x8 bK = *(const bf16x8*)(&Klds[s * 16 + lcol][grp * 8]);
            sc0[s] = __builtin_amdgcn_mfma_f32_16x16x32_bf16(aQ0, bK, zero, 0, 0, 0);
            sc1[s] = __builtin_amdgcn_mfma_f32_16x16x32_bf16(aQ1, bK, zero, 0, 0, 0);
        }
        float mymax = sc0[0][0];
#pragma unroll
        for (int s = 0; s < 4; ++s)
#pragma unroll
            for (int r = 0; r < 4; ++r) {
                mymax = fmaxf(mymax, sc0[s][r]);
                mymax = fmaxf(mymax, sc1[s][r]);
            }
        mymax = fmaxf(mymax, __shfl_xor(mymax, 1));
        mymax = fmaxf(mymax, __shfl_xor(mymax, 2));
        mymax = fmaxf(mymax, __shfl_xor(mymax, 4));
        mymax = fmaxf(mymax, __shfl_xor(mymax, 8));
        float mnew = fmaxf(msh, mymax * C1);
        float cc = __builtin_exp2f(msh - mnew);
        msh = mnew;
#pragma unroll
        for (int r = 0; r < 4; ++r) {
            float p0 = __builtin_exp2f(__builtin_fmaf(sc0[0][r], C1, -mnew));
            float p1 = __builtin_exp2f(__builtin_fmaf(sc0[1][r], C1, -mnew));
            float p2 = __builtin_exp2f(__builtin_fmaf(sc0[2][r], C1, -mnew));
            float p3 = __builtin_exp2f(__builtin_fmaf(sc0[3][r], C1, -mnew));
            u32 a01 = __builtin_amdgcn_perm(__float_as_uint(p1), __float_as_uint(p0), 0x07060302u);
            u32 a23 = __builtin_amdgcn_perm(__float_as_uint(p3), __float_as_uint(p2), 0x07060302u);
            *(uint2*)(&Plds[wave][grp * 4 + r][4 * lcol]) = make_uint2(a01, a23);
            float q0 = __builtin_exp2f(__builtin_fmaf(sc1[0][r], C1, -mnew));
            float q1 = __builtin_exp2f(__builtin_fmaf(sc1[1][r], C1, -mnew));
            float q2 = __builtin_exp2f(__builtin_fmaf(sc1[2][r], C1, -mnew));
            float q3 = __builtin_exp2f(__builtin_fmaf(sc1[3][r], C1, -mnew));
            u32 b01 = __builtin_amdgcn_perm(__float_as_uint(q1), __float_as_uint(q0), 0x07060302u);
            u32 b23 = __builtin_amdgcn_perm(__float_as_uint(q3), __float_as_uint(q2), 0x07060302u);
            *(uint2*)(&Plds[wave][16 + grp * 4 + r][4 * lcol]) = make_uint2(b01, b23);
        }
        oc00 *= cc; oc01 *= cc; ol0 *= cc;
        oc10 *= cc; oc11 *= cc; ol1 *= cc;
#pragma unroll
        for (int c2 = 0; c2 < 2; ++c2) {
            bf16x8 aP0 = *(const bf16x8*)(&Plds[wave][lcol][c2 * 32 + grp * 8]);
            bf16x8 aP1 = *(const bf16x8*)(&Plds[wave][16 + lcol][c2 * 32 + grp * 8]);
            bf16x8 bV0 = *(const bf16x8*)(&Vlds[lcol][c2 * 16 + grp * 4]);
            bf16x8 bV1 = *(const bf16x8*)(&Vlds[16 + lcol][c2 * 16 + grp * 4]);
            oc00 = __builtin_amdgcn_mfma_f32_16x16x32_bf16(aP0, bV0, oc00, 0, 0, 0);
            oc01 = __builtin_amdgcn_mfma_f32_16x16x32_bf16(aP0, bV1, oc01, 0, 0, 0);
            ol0 = __builtin_amdgcn_mfma_f32_16x16x32_bf16(aP0, bOne, ol0, 0, 0, 0);
            oc10 = __builtin_amdgcn_mfma_f32_16x16x32_bf16(aP1, bV0, oc10, 0, 0, 0);
            oc11 = __builtin_amdgcn_mfma_f32_16x16x32_bf16(aP1, bV1, oc11, 0, 0, 0);
            ol1 = __builtin_amdgcn_mfma_f32_16x16x32_bf16(aP1, bOne, ol1, 0, 0, 0);
        }
        __syncthreads();
    }
#pragma unroll
    for (int r = 0; r < 4; ++r) {
        int row0 = qrow0 + grp * 4 + r;
        size_t b0 = ((size_t)row0 * HEADS + head) * KSPLIT + ks;
        PO[b0 * 32 + lcol] = f2bf(oc00[r]);
        PO[b0 * 32 + 16 + lcol] = f2bf(oc01[r]);
        int row1 = row0 + 16;
        size_t b1 = ((size_t)row1 * HEADS + head) * KSPLIT + ks;
        PO[b1 * 32 + lcol] = f2bf(oc10[r]);
        PO[b1 * 32 + 16 + lcol] = f2bf(oc11[r]);
        if (lcol == 0) {
            PM[b0] = msh;
            PL[b0] = ol0[r];
            PM[b1] = msh;
            PL[b1] = ol1[r];
        }
    }
}

__global__ void k_mha_comb(const float* __restrict__ PM, const float* __restrict__ PL,
                           const u16* __restrict__ PO, u16* __restrict__ atthi,
                           u16* __restrict__ attlo) {
    int t = blockIdx.x * 256 + threadIdx.x;
    if (t >= NN * HH) return;
    int row = t >> 7, col = t & 127;
    int head = col >> 5, dim = col & 31;
    size_t b0 = ((size_t)row * HEADS + head) * KSPLIT;
    float m = -INFINITY;
#pragma unroll
    for (int k = 0; k < KSPLIT; ++k) m = fmaxf(m, PM[b0 + k]);
    float l = 0.f, o = 0.f;
#pragma unroll
    for (int k = 0; k < KSPLIT; ++k) {
        float w = __builtin_exp2f(PM[b0 + k] - m);
        l += PL[b0 + k] * w;
        o += bf2f(PO[(b0 + k) * 32 + dim]) * w;
    }
    float v = o / l;
    u16 h = f2bf(v);
    atthi[t] = h;
    attlo[t] = f2bf(v - bf2f(h));
}

// ---------------- output projection ----------------
__global__ __launch_bounds__(64) void k_out(const float* __restrict__ h, const float* __restrict__ w,
                                            const float* __restrict__ b, void* __restrict__ yout,
                                            const int* __restrict__ flag) {
    int n = blockIdx.x, l = threadIdx.x;
    float a0 = 0.f, a1 = 0.f;
    for (int k = l; k < HH; k += 64) {
        float hv = h[(size_t)n * HH + k];
        a0 += hv * w[k];
        a1 += hv * w[HH + k];
    }
#pragma unroll
    for (int off = 32; off > 0; off >>= 1) {
        a0 += __shfl_xor(a0, off);
        a1 += __shfl_xor(a1, off);
    }
    if (l == 0) {
        float o0 = a0 + b[0], o1 = a1 + b[1];
        if (*flag) {
            u16* y = (u16*)yout;
            y[n * 2 + 0] = f2bf(o0);
            y[n * 2 + 1] = f2bf(o1);
        } else {
            float* y = (float*)yout;
            y[n * 2 + 0] = o0;
            y[n * 2 + 1] = o1;
        }
    }
}

extern "C" void kernel_launch(void* const* d_in, const int* in_sizes, int n_in,
                              void* d_out, int out_size, void* d_ws, size_t ws_size,
                              hipStream_t stream) {
    float* W = (float*)d_ws;
    size_t o = 0;
    auto take = [&](size_t n) { size_t r = o; o += n; return r; };
    size_t pb_in = take(HH);
    size_t pattS = take(LL * HEADS * DH);
    size_t pattD = take(LL * HEADS * DH);
    size_t pb_gat = take(LL * HH);
    size_t pb_qkv = take(LL * 3 * HH);
    size_t pb_o  = take(LL * HH);
    size_t pbn_g = take(LL * 3 * HH);
    size_t pbn_b = take(LL * 3 * HH);
    size_t pb1   = take(LL * 2 * HH);
    size_t pb2   = take(LL * HH);
    size_t pw_out = take(2 * HH);
    size_t pb_out = take(2);
    auto takeb = [&](size_t nu16) { size_t r = o; o += (nu16 + 1) / 2; return r; };
    size_t bw_in  = takeb(HH * INF_);
    size_t bw_gat = takeb(LL * HH * HH);
    size_t bw_qkv = takeb(LL * 3 * HH * HH);
    size_t bw_o   = takeb(LL * HH * HH);
    size_t bw1    = takeb(LL * 2 * HH * HH);
    size_t bw2    = takeb(LL * HH * 2 * HH);
    o = (o + 127) & ~(size_t)127;
    size_t ohbuf = take(NH);
    size_t ogat  = take(NH);
    size_t otmp  = take(NH);
    size_t oals  = take(NN * HEADS);
    size_t oald  = take(NN * HEADS);
    size_t opm   = take(NN * HEADS * KSPLIT);
    size_t opl   = take(NN * HEADS * KSPLIT);
    size_t opo   = takeb((size_t)NN * HEADS * KSPLIT * 32);
    size_t oqkvb = takeb(NN * 384);
    size_t oxpb  = takeb(NH);
    size_t oxhi  = takeb(NN * INF_);
    size_t oxlo  = takeb(NN * INF_);
    size_t ohhi  = takeb(NH);
    size_t ohlo  = takeb(NH);
    size_t oahi  = takeb(NH);
    size_t oalo  = takeb(NH);
    size_t oohi  = takeb(NH);
    size_t oolo  = takeb(NH);
    size_t omhi  = takeb(NN * 2 * HH);
    size_t omlo  = takeb(NN * 2 * HH);
    int* ibase    = (int*)(W + o);
    int* iflag    = ibase;
    int* cnt      = ibase + 64;
    int* rowstart = cnt + NN;
    int* cursor   = rowstart + NN;
    int* esrc     = cursor + NN;
    u32* gmax     = (u32*)(esrc + EE);

    float* hbuf = W + ohbuf;
    float* gatb = W + ogat;
    float* tmp  = W + otmp;
    float* als  = W + oals;
    float* ald  = W + oald;
    float* pmb  = W + opm;
    float* plb  = W + opl;
    u16* pob  = (u16*)(W + opo);
    u16* qkvb = (u16*)(W + oqkvb);
    u16* xpb  = (u16*)(W + oxpb);
    u16* xhi = (u16*)(W + oxhi), *xlo = (u16*)(W + oxlo);
    u16* hhi = (u16*)(W + ohhi), *hlo = (u16*)(W + ohlo);
    u16* ahi = (u16*)(W + oahi), *alo = (u16*)(W + oalo);
    u16* ohi = (u16*)(W + oohi), *olo = (u16*)(W + oolo);
    u16* mhi = (u16*)(W + omhi), *mlo = (u16*)(W + omlo);

    const int* src = (const int*)d_in[1];
    const int* dst = (const int*)d_in[1] + EE;
    const u16* dw_in  = (const u16*)d_in[2];
    const u16* dw_gat = (const u16*)d_in[4];
    const u16* dw_qkv = (const u16*)d_in[8];
    const u16* dw_o   = (const u16*)d_in[10];
    const u16* dw1    = (const u16*)d_in[14];
    const u16* dw2    = (const u16*)d_in[16];

    k_detect<<<1, 256, 0, stream>>>((const u16*)d_in[0], iflag, cnt, gmax);

    SegF SF = {};
    int nf = 0;
    auto addf = [&](int idx, size_t off, int n) { SF.src[nf] = d_in[idx]; SF.dst[nf] = (int)off; SF.n[nf] = n; ++nf; };
    addf(3, pb_in, HH);
    addf(5, pattS, LL * HEADS * DH);
    addf(6, pattD, LL * HEADS * DH);
    addf(7, pb_gat, LL * HH);
    addf(9, pb_qkv, LL * 3 * HH);
    addf(11, pb_o, LL * HH);
    addf(12, pbn_g, LL * 3 * HH);
    addf(13, pbn_b, LL * 3 * HH);
    addf(15, pb1, LL * 2 * HH);
    addf(17, pb2, LL * HH);
    addf(18, pw_out, 2 * HH);
    addf(19, pb_out, 2);
    SF.cnt = nf;
    k_cvtf<<<dim3(8, nf), 256, 0, stream>>>(SF, W, iflag);

    SegB SB = {};
    int nb = 0;
    auto addb = [&](int idx, size_t off, int n, u16* d2) {
        SB.src[nb] = d_in[idx]; SB.dst[nb] = (u16*)(W + off); SB.dst2[nb] = d2; SB.n[nb] = n; ++nb;
    };
    addb(2, bw_in, HH * INF_, nullptr);
    addb(4, bw_gat, LL * HH * HH, nullptr);
    addb(8, bw_qkv, LL * 3 * HH * HH, nullptr);
    addb(10, bw_o, LL * HH * HH, nullptr);
    addb(14, bw1, LL * 2 * HH * HH, nullptr);
    addb(16, bw2, LL * HH * 2 * HH, nullptr);
    SB.src[nb] = d_in[0]; SB.dst[nb] = xhi; SB.dst2[nb] = xlo; SB.n[nb] = NN * INF_; ++nb;
    SB.cnt = nb;
    k_cvtb<<<dim3(128, nb), 256, 0, stream>>>(SB, iflag);

    k_hist<<<EE / 256, 256, 0, stream>>>(dst, cnt);
    k_scan<<<1, 256, 0, stream>>>(cnt, rowstart, cursor);
    k_scatter<<<EE / 256, 256, 0, stream>>>(src, dst, cursor, esrc);

    k_mgemm<<<dim3(NN / 32, HH / 64), 128, 0, stream>>>(xhi, xlo, (u16*)(W + bw_in), dw_in, iflag,
                                                        W + pb_in, hbuf, nullptr, hhi, hlo, INF_, HH, 1);

    for (int l = 0; l < LL; ++l) {
        k_gemm_gq<<<dim3(NN / 32, 8), 128, 0, stream>>>(hhi, hlo,
                                                        (u16*)(W + bw_gat) + (size_t)l * HH * HH,
                                                        dw_gat + (size_t)l * HH * HH,
                                                        (u16*)(W + bw_qkv) + (size_t)l * 3 * HH * HH,
                                                        dw_qkv + (size_t)l * 3 * HH * HH,
                                                        iflag, W + pb_qkv + l * 3 * HH, xpb, qkvb);
        k_attlog<<<(NN * HEADS) / 256, 256, 0, stream>>>(xpb, W + pattS + l * HEADS * DH,
                                                         W + pattD + l * HEADS * DH, als, ald,
                                                         gmax + l * 8);
        k_gat_node<<<NN, 128, 0, stream>>>(esrc, rowstart, cnt, als, ald, xpb, gatb, gmax + l * 8);
        k_mha_split<<<(NN / 128) * HEADS * KSPLIT, 256, 0, stream>>>(qkvb, pmb, plb, pob);
        k_mha_comb<<<(NN * HH) / 256, 256, 0, stream>>>(pmb, plb, pob, ahi, alo);
        k_gemm_wo<<<dim3(NN / 32, HH / 64), 128, 0, stream>>>(ahi, alo,
                                                              (u16*)(W + bw_o) + (size_t)l * HH * HH,
                                                              dw_o + (size_t)l * HH * HH, iflag,
                                                              W + pb_o + l * HH, gatb, hbuf,
                                                              W + pb_gat + l * HH, W + pbn_g + l * 3 * HH,
                                                              W + pbn_b + l * 3 * HH, tmp, ohi, olo);
        k_mgemm<<<dim3(NN / 32, 256 / 64), 128, 0, stream>>>(ohi, olo,
                                                             (u16*)(W + bw1) + (size_t)l * 2 * HH * HH,
                                                             dw1 + (size_t)l * 2 * HH * HH, iflag,
                                                             W + pb1 + l * 2 * HH, nullptr, nullptr,
                                                             mhi, mlo, HH, 2 * HH, 1);
        k_gemm_w2<<<dim3(NN / 32, HH / 64), 128, 0, stream>>>(mhi, mlo,
                                                              (u16*)(W + bw2) + (size_t)l * HH * 2 * HH,
                                                              dw2 + (size_t)l * HH * 2 * HH, iflag,
                                                              W + pb2 + l * HH, tmp,
                                                              W + pbn_g + l * 3 * HH + 2 * HH,
                                                              W + pbn_b + l * 3 * HH + 2 * HH,
                                                              hbuf, hhi, hlo);
    }
    k_out<<<NN, 64, 0, stream>>>(hbuf, W + pw_out, W + pb_out, d_out, iflag);
}

// Round 13
// 322.709 us; speedup vs baseline: 1.0615x; 1.0071x over previous
//
#include <hip/hip_runtime.h>

#define NN 4096
#define EE 262144
#define INF_ 64
#define HH 128
#define HEADS 4
#define DH 32
#define LL 2
#define NH (NN * HH)
#define KSPLIT 16
#define L2E 1.4426950408889634f

typedef unsigned short u16;
typedef unsigned int u32;
using bf16x8 = __attribute__((ext_vector_type(8))) short;
using f32x4 = __attribute__((ext_vector_type(4))) float;

__device__ __forceinline__ float bf2f(u16 v) { return __uint_as_float(((u32)v) << 16); }
__device__ __forceinline__ u16 f2bf(float f) {
    u32 u = __float_as_uint(f);
    u32 r = (u + 0x7fffu + ((u >> 16) & 1u)) >> 16;
    return (u16)r;
}
__device__ __forceinline__ u32 encf(float f) {
    u32 b = __float_as_uint(f);
    return (b & 0x80000000u) ? ~b : (b | 0x80000000u);
}
__device__ __forceinline__ float decf(u32 u) {
    u32 b = (u & 0x80000000u) ? (u & 0x7fffffffu) : ~u;
    return __uint_as_float(b);
}

// ---------------- dtype detect + zero-init (cnt, gmax) ----------------
__global__ __launch_bounds__(256) void k_detect(const u16* __restrict__ x, int* __restrict__ flag,
                                                int* __restrict__ cnt, u32* __restrict__ gmax) {
    int t = threadIdx.x;
    for (int i = t; i < NN; i += 256) cnt[i] = 0;
    if (t < 16) gmax[t] = 0;
    __shared__ int cs[256];
    u16 v = x[2 * t];
    int e = (v >> 7) & 0xFF;
    cs[t] = (e >= 100 && e <= 140) ? 1 : 0;
    __syncthreads();
    for (int s = 128; s > 0; s >>= 1) {
        if (t < s) cs[t] += cs[t + s];
        __syncthreads();
    }
    if (t == 0) *flag = (cs[0] >= 128) ? 1 : 0;
}

// ---------------- batched param conversion ----------------
#define MAXSEG 16
struct SegF { const void* src[MAXSEG]; int dst[MAXSEG]; int n[MAXSEG]; int cnt; };
__global__ void k_cvtf(SegF S, float* __restrict__ W, const int* __restrict__ flag) {
    int seg = blockIdx.y;
    if (seg >= S.cnt) return;
    int n = S.n[seg];
    float* d = W + S.dst[seg];
    const void* s = S.src[seg];
    int f = *flag;
    for (int i = blockIdx.x * 256 + threadIdx.x; i < n; i += gridDim.x * 256)
        d[i] = f ? bf2f(((const u16*)s)[i]) : ((const float*)s)[i];
}
struct SegB { const void* src[8]; u16* dst[8]; u16* dst2[8]; int n[8]; int cnt; };
__global__ void k_cvtb(SegB S, const int* __restrict__ flag) {
    int seg = blockIdx.y;
    if (seg >= S.cnt) return;
    int f = *flag;
    u16* d = S.dst[seg];
    u16* d2 = S.dst2[seg];
    if (f && !d2) return;   // weights already bf16 in d_in
    int n = S.n[seg];
    const void* s = S.src[seg];
    for (int i = blockIdx.x * 256 + threadIdx.x; i < n; i += gridDim.x * 256) {
        if (d2) {
            float v = f ? bf2f(((const u16*)s)[i]) : ((const float*)s)[i];
            u16 h = f2bf(v);
            d[i] = h;
            d2[i] = f2bf(v - bf2f(h));
        } else {
            d[i] = f2bf(((const float*)s)[i]);
        }
    }
}

// ---------------- CSR build ----------------
__global__ void k_hist(const int* __restrict__ dst, int* __restrict__ cnt) {
    int e = blockIdx.x * blockDim.x + threadIdx.x;
    if (e < EE) atomicAdd(&cnt[dst[e]], 1);
}
__global__ __launch_bounds__(256) void k_scan(const int* __restrict__ cnt, int* __restrict__ rowstart,
                                              int* __restrict__ cursor) {
    __shared__ int part[256];
    int t = threadIdx.x;
    int loc[16];
    int s = 0;
#pragma unroll
    for (int i = 0; i < 16; ++i) { loc[i] = s; s += cnt[t * 16 + i]; }
    part[t] = s;
    __syncthreads();
    for (int off = 1; off < 256; off <<= 1) {
        int v = part[t];
        int a = (t >= off) ? part[t - off] : 0;
        __syncthreads();
        part[t] = v + a;
        __syncthreads();
    }
    int base = (t == 0) ? 0 : part[t - 1];
#pragma unroll
    for (int i = 0; i < 16; ++i) {
        rowstart[t * 16 + i] = base + loc[i];
        cursor[t * 16 + i] = base + loc[i];
    }
}
__global__ void k_scatter(const int* __restrict__ src, const int* __restrict__ dst,
                          int* __restrict__ cursor, int* __restrict__ esrc) {
    int e = blockIdx.x * blockDim.x + threadIdx.x;
    if (e < EE) {
        int d = dst[e];
        int p = atomicAdd(&cursor[d], 1);
        esrc[p] = src[e];
    }
}

// ---------------- generic MFMA GEMM, M-tile 32, runtime weight select ----------------
__global__ __launch_bounds__(128) void k_mgemm(const u16* __restrict__ Ahi, const u16* __restrict__ Alo,
                                               const u16* __restrict__ Wc, const u16* __restrict__ Wd,
                                               const int* __restrict__ flag,
                                               const float* __restrict__ bias,
                                               float* __restrict__ outf, u16* __restrict__ outb16,
                                               u16* __restrict__ outhi, u16* __restrict__ outlo,
                                               int K, int J, int relu) {
    const u16* Wb = (*flag) ? Wd : Wc;
    int wave = threadIdx.x >> 6, lane = threadIdx.x & 63;
    int grp = lane >> 4, lcol = lane & 15;
    int m0 = blockIdx.x * 32 + wave * 16;
    int j0 = blockIdx.y * 64;
    f32x4 acc[4];
#pragma unroll
    for (int s = 0; s < 4; ++s) acc[s] = (f32x4){0.f, 0.f, 0.f, 0.f};
    const u16* ah = Ahi + (size_t)(m0 + lcol) * K + grp * 8;
    const u16* al = Alo + (size_t)(m0 + lcol) * K + grp * 8;
    const u16* wb = Wb + (size_t)(j0 + lcol) * K + grp * 8;
    for (int k = 0; k < K; k += 32) {
        bf16x8 va = *(const bf16x8*)(ah + k);
        bf16x8 vl = *(const bf16x8*)(al + k);
#pragma unroll
        for (int s = 0; s < 4; ++s) {
            bf16x8 vw = *(const bf16x8*)(wb + (size_t)s * 16 * K + k);
            acc[s] = __builtin_amdgcn_mfma_f32_16x16x32_bf16(va, vw, acc[s], 0, 0, 0);
            acc[s] = __builtin_amdgcn_mfma_f32_16x16x32_bf16(vl, vw, acc[s], 0, 0, 0);
        }
    }
#pragma unroll
    for (int s = 0; s < 4; ++s) {
        int col = j0 + s * 16 + lcol;
        float bs = bias ? bias[col] : 0.f;
#pragma unroll
        for (int r = 0; r < 4; ++r) {
            float v = acc[s][r] + bs;
            if (relu) v = fmaxf(v, 0.f);
            size_t idx = (size_t)(m0 + grp * 4 + r) * J + col;
            if (outf) outf[idx] = v;
            if (outb16) outb16[idx] = f2bf(v);
            if (outhi) {
                u16 hv = f2bf(v);
                outhi[idx] = hv;
                outlo[idx] = f2bf(v - bf2f(hv));
            }
        }
    }
}

// ---------------- fused GAT-xp + QKV GEMM ----------------
__global__ __launch_bounds__(128) void k_gemm_gq(const u16* __restrict__ Ahi, const u16* __restrict__ Alo,
                                                 const u16* __restrict__ wgatc, const u16* __restrict__ wgatd,
                                                 const u16* __restrict__ wqkvc, const u16* __restrict__ wqkvd,
                                                 const int* __restrict__ flag,
                                                 const float* __restrict__ bqkv,
                                                 u16* __restrict__ xpb, u16* __restrict__ qkvb) {
    int wave = threadIdx.x >> 6, lane = threadIdx.x & 63;
    int grp = lane >> 4, lcol = lane & 15;
    int m0 = blockIdx.x * 32 + wave * 16;
    int jb = blockIdx.y;
    int j0 = jb * 64;
    int f = *flag;
    const u16* wgat = f ? wgatd : wgatc;
    const u16* wqkv = f ? wqkvd : wqkvc;
    const u16* Wb = (jb < 2) ? (wgat + (size_t)j0 * HH) : (wqkv + (size_t)(j0 - 128) * HH);
    f32x4 acc[4];
#pragma unroll
    for (int s = 0; s < 4; ++s) acc[s] = (f32x4){0.f, 0.f, 0.f, 0.f};
    const u16* ah = Ahi + (size_t)(m0 + lcol) * HH + grp * 8;
    const u16* al = Alo + (size_t)(m0 + lcol) * HH + grp * 8;
    const u16* wb = Wb + (size_t)lcol * HH + grp * 8;
    for (int k = 0; k < HH; k += 32) {
        bf16x8 va = *(const bf16x8*)(ah + k);
        bf16x8 vl = *(const bf16x8*)(al + k);
#pragma unroll
        for (int s = 0; s < 4; ++s) {
            bf16x8 vw = *(const bf16x8*)(wb + (size_t)s * 16 * HH + k);
            acc[s] = __builtin_amdgcn_mfma_f32_16x16x32_bf16(va, vw, acc[s], 0, 0, 0);
            acc[s] = __builtin_amdgcn_mfma_f32_16x16x32_bf16(vl, vw, acc[s], 0, 0, 0);
        }
    }
    if (jb < 2) {
#pragma unroll
        for (int s = 0; s < 4; ++s) {
            int col = j0 + s * 16 + lcol;
#pragma unroll
            for (int r = 0; r < 4; ++r)
                xpb[(size_t)(m0 + grp * 4 + r) * HH + col] = f2bf(acc[s][r]);
        }
    } else {
#pragma unroll
        for (int s = 0; s < 4; ++s) {
            int colq = j0 - 128 + s * 16 + lcol;
            float bs = bqkv[colq];
#pragma unroll
            for (int r = 0; r < 4; ++r)
                qkvb[(size_t)(m0 + grp * 4 + r) * 384 + colq] = f2bf(acc[s][r] + bs);
        }
    }
}

// ---------------- attlog (bf16 xp) + per-head global-max atomics ----------------
__global__ __launch_bounds__(256) void k_attlog(const u16* __restrict__ xpb, const float* __restrict__ asrc,
                                                const float* __restrict__ adst, float* __restrict__ als,
                                                float* __restrict__ ald, u32* __restrict__ gmax) {
    int t = blockIdx.x * 256 + threadIdx.x;
    int n = t >> 2, hh = t & 3;
    const u16* xr = xpb + (size_t)n * HH + hh * DH;
    float s1 = 0.f, s2 = 0.f;
#pragma unroll
    for (int d = 0; d < DH; ++d) {
        float v = bf2f(xr[d]);
        s1 += v * asrc[hh * DH + d];
        s2 += v * adst[hh * DH + d];
    }
    als[t] = s1;
    ald[t] = s2;
    __shared__ float red[256];
    int lt = threadIdx.x;
    red[lt] = s1;
    __syncthreads();
    for (int off = 128; off >= 4; off >>= 1) {
        if (lt < off) red[lt] = fmaxf(red[lt], red[lt + off]);
        __syncthreads();
    }
    if (lt < 4) atomicMax(&gmax[lt], encf(red[lt]));
    __syncthreads();
    red[lt] = s2;
    __syncthreads();
    for (int off = 128; off >= 4; off >>= 1) {
        if (lt < off) red[lt] = fmaxf(red[lt], red[lt + off]);
        __syncthreads();
    }
    if (lt < 4) atomicMax(&gmax[4 + lt], encf(red[lt]));
}

// ---------------- w_o GEMM + combine fused epilogue ----------------
__global__ __launch_bounds__(128) void k_gemm_wo(const u16* __restrict__ Ahi, const u16* __restrict__ Alo,
                                                 const u16* __restrict__ Wc, const u16* __restrict__ Wd,
                                                 const int* __restrict__ flag,
                                                 const float* __restrict__ bias,
                                                 const float* __restrict__ gatb, const float* __restrict__ hbuf,
                                                 const float* __restrict__ bgat, const float* __restrict__ gam,
                                                 const float* __restrict__ bet,
                                                 float* __restrict__ outb, u16* __restrict__ ohi,
                                                 u16* __restrict__ olo) {
    const u16* Wb = (*flag) ? Wd : Wc;
    int wave = threadIdx.x >> 6, lane = threadIdx.x & 63;
    int grp = lane >> 4, lcol = lane & 15;
    int m0 = blockIdx.x * 32 + wave * 16;
    int j0 = blockIdx.y * 64;
    f32x4 acc[4];
#pragma unroll
    for (int s = 0; s < 4; ++s) acc[s] = (f32x4){0.f, 0.f, 0.f, 0.f};
    const u16* ah = Ahi + (size_t)(m0 + lcol) * HH + grp * 8;
    const u16* al = Alo + (size_t)(m0 + lcol) * HH + grp * 8;
    const u16* wb = Wb + (size_t)(j0 + lcol) * HH + grp * 8;
    for (int k = 0; k < HH; k += 32) {
        bf16x8 va = *(const bf16x8*)(ah + k);
        bf16x8 vl = *(const bf16x8*)(al + k);
#pragma unroll
        for (int s = 0; s < 4; ++s) {
            bf16x8 vw = *(const bf16x8*)(wb + (size_t)s * 16 * HH + k);
            acc[s] = __builtin_amdgcn_mfma_f32_16x16x32_bf16(va, vw, acc[s], 0, 0, 0);
            acc[s] = __builtin_amdgcn_mfma_f32_16x16x32_bf16(vl, vw, acc[s], 0, 0, 0);
        }
    }
    float rs = rsqrtf(1.00001f);
#pragma unroll
    for (int s = 0; s < 4; ++s) {
        int col = j0 + s * 16 + lcol;
        float bs = bias[col];
        float g0 = gam[col] * rs, b0 = bet[col];
        float g1 = gam[HH + col] * rs, b1 = bet[HH + col];
        float bg = bgat[col];
#pragma unroll
        for (int r = 0; r < 4; ++r) {
            size_t idx = (size_t)(m0 + grp * 4 + r) * HH + col;
            float proj = acc[s][r] + bs;
            float hv = hbuf[idx];
            float hl = g0 * (gatb[idx] + bg + hv) + b0;
            float ha = g1 * (proj + hv) + b1;
            float v = hl + ha;
            outb[idx] = v;
            u16 hb = f2bf(v);
            ohi[idx] = hb;
            olo[idx] = f2bf(v - bf2f(hb));
        }
    }
}

// ---------------- w2 GEMM + final fused epilogue ----------------
__global__ __launch_bounds__(128) void k_gemm_w2(const u16* __restrict__ Ahi, const u16* __restrict__ Alo,
                                                 const u16* __restrict__ Wc, const u16* __restrict__ Wd,
                                                 const int* __restrict__ flag,
                                                 const float* __restrict__ bias,
                                                 const float* __restrict__ outb, const float* __restrict__ gam2,
                                                 const float* __restrict__ bet2,
                                                 float* __restrict__ hbuf, u16* __restrict__ hhi,
                                                 u16* __restrict__ hlo) {
    const u16* Wb = (*flag) ? Wd : Wc;
    int wave = threadIdx.x >> 6, lane = threadIdx.x & 63;
    int grp = lane >> 4, lcol = lane & 15;
    int m0 = blockIdx.x * 32 + wave * 16;
    int j0 = blockIdx.y * 64;
    const int K = 2 * HH;
    f32x4 acc[4];
#pragma unroll
    for (int s = 0; s < 4; ++s) acc[s] = (f32x4){0.f, 0.f, 0.f, 0.f};
    const u16* ah = Ahi + (size_t)(m0 + lcol) * K + grp * 8;
    const u16* al = Alo + (size_t)(m0 + lcol) * K + grp * 8;
    const u16* wb = Wb + (size_t)(j0 + lcol) * K + grp * 8;
    for (int k = 0; k < K; k += 32) {
        bf16x8 va = *(const bf16x8*)(ah + k);
        bf16x8 vl = *(const bf16x8*)(al + k);
#pragma unroll
        for (int s = 0; s < 4; ++s) {
            bf16x8 vw = *(const bf16x8*)(wb + (size_t)s * 16 * K + k);
            acc[s] = __builtin_amdgcn_mfma_f32_16x16x32_bf16(va, vw, acc[s], 0, 0, 0);
            acc[s] = __builtin_amdgcn_mfma_f32_16x16x32_bf16(vl, vw, acc[s], 0, 0, 0);
        }
    }
    float rs = rsqrtf(1.00001f);
#pragma unroll
    for (int s = 0; s < 4; ++s) {
        int col = j0 + s * 16 + lcol;
        float bs = bias[col];
        float g2 = gam2[col] * rs, b2 = bet2[col];
#pragma unroll
        for (int r = 0; r < 4; ++r) {
            size_t idx = (size_t)(m0 + grp * 4 + r) * HH + col;
            float mlpo = acc[s][r] + bs;
            float o2 = g2 * (outb[idx] + mlpo) + b2;
            float v = fmaxf(o2 + hbuf[idx], 0.f);
            hbuf[idx] = v;
            u16 hb = f2bf(v);
            hhi[idx] = hb;
            hlo[idx] = f2bf(v - bf2f(hb));
        }
    }
}

// ---------------- GAT: single fused pass with global-max bound ----------------
#define GCHUNK 256
__global__ __launch_bounds__(128) void k_gat_node(const int* __restrict__ esrc, const int* __restrict__ rowstart,
                                                  const int* __restrict__ cnt, const float* __restrict__ als,
                                                  const float* __restrict__ ald, const u16* __restrict__ xpb,
                                                  float* __restrict__ gatout, const u32* __restrict__ gmax) {
    int n = blockIdx.x, t = threadIdx.x;
    int base = rowstart[n], c = cnt[n];
    float4 adv = ((const float4*)ald)[n];
    float ad[4] = {adv.x, adv.y, adv.z, adv.w};
    float M2[4];
#pragma unroll
    for (int h = 0; h < 4; ++h) {
        float bound = decf(gmax[h]) + decf(gmax[4 + h]);
        float M = bound >= 0.f ? bound : 0.2f * bound;
        M2[h] = M * L2E;
    }
    __shared__ float red[512];
    __shared__ float elds[GCHUNK * 4];
    __shared__ int slds[GCHUNK];
    float dsum[4] = {0.f, 0.f, 0.f, 0.f};
    float acc = 0.f;
    int ht = t >> 5;
    for (int ch = 0; ch < c; ch += GCHUNK) {
        int cn = min(GCHUNK, c - ch);
        __syncthreads();
        for (int i = t; i < cn; i += 128) {
            int s = esrc[base + ch + i];
            slds[i] = s;
            float4 as = ((const float4*)als)[s];
            float lg, e;
            lg = as.x + ad[0]; lg = lg >= 0.f ? lg : 0.2f * lg; e = __builtin_exp2f(lg * L2E - M2[0]); elds[i * 4 + 0] = e; dsum[0] += e;
            lg = as.y + ad[1]; lg = lg >= 0.f ? lg : 0.2f * lg; e = __builtin_exp2f(lg * L2E - M2[1]); elds[i * 4 + 1] = e; dsum[1] += e;
            lg = as.z + ad[2]; lg = lg >= 0.f ? lg : 0.2f * lg; e = __builtin_exp2f(lg * L2E - M2[2]); elds[i * 4 + 2] = e; dsum[2] += e;
            lg = as.w + ad[3]; lg = lg >= 0.f ? lg : 0.2f * lg; e = __builtin_exp2f(lg * L2E - M2[3]); elds[i * 4 + 3] = e; dsum[3] += e;
        }
        __syncthreads();
        int i = 0;
        for (; i + 4 <= cn; i += 4) {
            int s0 = slds[i], s1 = slds[i + 1], s2 = slds[i + 2], s3 = slds[i + 3];
            float x0 = bf2f(xpb[(size_t)s0 * HH + t]);
            float x1 = bf2f(xpb[(size_t)s1 * HH + t]);
            float x2 = bf2f(xpb[(size_t)s2 * HH + t]);
            float x3 = bf2f(xpb[(size_t)s3 * HH + t]);
            acc += elds[i * 4 + ht] * x0 + elds[(i + 1) * 4 + ht] * x1;
            acc += elds[(i + 2) * 4 + ht] * x2 + elds[(i + 3) * 4 + ht] * x3;
        }
        for (; i < cn; ++i) acc += elds[i * 4 + ht] * bf2f(xpb[(size_t)slds[i] * HH + t]);
    }
    __syncthreads();
#pragma unroll
    for (int h = 0; h < 4; ++h) red[h * 128 + t] = dsum[h];
    __syncthreads();
    for (int s2 = 64; s2 > 0; s2 >>= 1) {
        if (t < s2) {
#pragma unroll
            for (int h = 0; h < 4; ++h)
                red[h * 128 + t] += red[h * 128 + t + s2];
        }
        __syncthreads();
    }
    float inv = 1.f / (red[ht * 128] + 1e-16f);
    gatout[(size_t)n * HH + t] = acc * inv;
}

// ---------------- MHA flash v6: 32-key P chunks (LDS 19 KB -> 8 blocks/CU) ----------------
// kappa32(c,key) = 2*(key&15) + ((key>>4)&1) within chunk c (keys c*32..c*32+31).
// Vlds u32[32][40]: [dim][c*20 + pair j] packs keys (c*32+j, c*32+16+j).
__global__ __launch_bounds__(256) void k_mha_split(const u16* __restrict__ qkvb,
                                                   float* __restrict__ PM, float* __restrict__ PL,
                                                   u16* __restrict__ PO) {
    const float C1 = 0.17677669529663687f * L2E;
    int head = blockIdx.x & 3;
    int qt = (blockIdx.x >> 2) & 31;
    int ks = blockIdx.x >> 7;
    int tid = threadIdx.x;
    int wave = tid >> 6, lane = tid & 63;
    int grp = lane >> 4, lcol = lane & 15;

    __shared__ __align__(16) u16 Klds[64][40];     // 5120 B
    __shared__ __align__(16) u32 Vlds[32][40];     // 5120 B
    __shared__ __align__(16) u16 Plds[4][32][36];  // 9216 B  (32 kappa32 + pad)

    int qrow0 = qt * 128 + wave * 32;
    bf16x8 aQ0 = *(const bf16x8*)(qkvb + (size_t)(qrow0 + lcol) * 384 + head * 32 + grp * 8);
    bf16x8 aQ1 = *(const bf16x8*)(qkvb + (size_t)(qrow0 + 16 + lcol) * 384 + head * 32 + grp * 8);

    short onev = (lcol == 0) ? (short)0x3F80 : (short)0;
    bf16x8 bOne = {onev, onev, onev, onev, onev, onev, onev, onev};

    f32x4 oc00 = {0.f, 0.f, 0.f, 0.f}, oc01 = {0.f, 0.f, 0.f, 0.f};
    f32x4 oc10 = {0.f, 0.f, 0.f, 0.f}, oc11 = {0.f, 0.f, 0.f, 0.f};
    f32x4 ol0 = {0.f, 0.f, 0.f, 0.f}, ol1 = {0.f, 0.f, 0.f, 0.f};
    float msh = -INFINITY;

    // staging: threads <128 stage K; threads >=128 stage V (chunked kappa layout)
    int isK = (tid < 128);
    int st = tid & 127;
    int skey = st >> 1, shalf = (st & 1) * 16;          // K map
    int vj = st & 15, vc = (st >> 4) & 1, dgrp = st >> 5;  // V map: pair j, chunk, dim-group(0..3)
    const u16* kptr = qkvb + 128 + head * 32 + shalf;
    const u16* vptr = qkvb + 256 + head * 32 + dgrp * 8;
    int vk0 = vc * 32 + vj;          // key for lo16
    int vk1 = vc * 32 + 16 + vj;     // key for hi16

    int kt0 = ks * (NN / KSPLIT);
    bf16x8 r0, r1;
    if (isK) {
        r0 = *(const bf16x8*)(kptr + (size_t)(kt0 + skey) * 384);
        r1 = *(const bf16x8*)(kptr + (size_t)(kt0 + skey) * 384 + 8);
    } else {
        r0 = *(const bf16x8*)(vptr + (size_t)(kt0 + vk0) * 384);
        r1 = *(const bf16x8*)(vptr + (size_t)(kt0 + vk1) * 384);
    }

    const int NT = (NN / KSPLIT) / 64;
    for (int t = 0; t < NT; ++t) {
        if (isK) {
            *(bf16x8*)(&Klds[skey][shalf]) = r0;
            *(bf16x8*)(&Klds[skey][shalf + 8]) = r1;
        } else {
#pragma unroll
            for (int j = 0; j < 8; ++j)
                Vlds[dgrp * 8 + j][vc * 20 + vj] = (u32)(u16)r0[j] | ((u32)(u16)r1[j] << 16);
        }
        __syncthreads();
        if (t + 1 < NT) {
            int kn = kt0 + (t + 1) * 64;
            if (isK) {
                r0 = *(const bf16x8*)(kptr + (size_t)(kn + skey) * 384);
                r1 = *(const bf16x8*)(kptr + (size_t)(kn + skey) * 384 + 8);
            } else {
                r0 = *(const bf16x8*)(vptr + (size_t)(kn + vk0) * 384);
                r1 = *(const bf16x8*)(vptr + (size_t)(kn + vk1) * 384);
            }
        }
        f32x4 sc0[4], sc1[4];
        f32x4 zero = {0.f, 0.f, 0.f, 0.f};
#pragma unroll
        for (int s = 0; s < 4; ++s) {
            bf16x8 bK = *(const bf16x8*)(&Klds[s * 16 + lcol][grp * 8]);
            sc0[s] = __builtin_amdgcn_mfma_f32_16x16x32_bf16(aQ0, bK, zero, 0, 0, 0);
            sc1[s] = __builtin_amdgcn_mfma_f32_16x16x32_bf16(aQ1, bK, zero, 0, 0, 0);
        }
        float mymax = sc0[0][0];
#pragma unroll
        for (int s = 0; s < 4; ++s)
#pragma unroll
            for (int r = 0; r < 4; ++r) {
                mymax = fmaxf(mymax, sc0[s][r]);
                mymax = fmaxf(mymax, sc1[s][r]);
            }
        mymax = fmaxf(mymax, __shfl_xor(mymax, 1));
        mymax = fmaxf(mymax, __shfl_xor(mymax, 2));
        mymax = fmaxf(mymax, __shfl_xor(mymax, 4));
        mymax = fmaxf(mymax, __shfl_xor(mymax, 8));
        float mnew = fmaxf(msh, mymax * C1);
        float cc = __builtin_exp2f(msh - mnew);
        msh = mnew;
        oc00 *= cc; oc01 *= cc; ol0 *= cc;
        oc10 *= cc; oc11 *= cc; ol1 *= cc;
        // two 32-key chunks: write P chunk (wave-private, no barrier) then PV
#pragma unroll
        for (int c2 = 0; c2 < 2; ++c2) {
#pragma unroll
            for (int r = 0; r < 4; ++r) {
                float p0 = __builtin_exp2f(__builtin_fmaf(sc0[2 * c2][r], C1, -mnew));
                float p1 = __builtin_exp2f(__builtin_fmaf(sc0[2 * c2 + 1][r], C1, -mnew));
                *(u32*)(&Plds[wave][grp * 4 + r][2 * lcol]) =
                    __builtin_amdgcn_perm(__float_as_uint(p1), __float_as_uint(p0), 0x07060302u);
                float q0 = __builtin_exp2f(__builtin_fmaf(sc1[2 * c2][r], C1, -mnew));
                float q1 = __builtin_exp2f(__builtin_fmaf(sc1[2 * c2 + 1][r], C1, -mnew));
                *(u32*)(&Plds[wave][16 + grp * 4 + r][2 * lcol]) =
                    __builtin_amdgcn_perm(__float_as_uint(q1), __float_as_uint(q0), 0x07060302u);
            }
            bf16x8 aP0 = *(const bf16x8*)(&Plds[wave][lcol][grp * 8]);
            bf16x8 aP1 = *(const bf16x8*)(&Plds[wave][16 + lcol][grp * 8]);
            bf16x8 bV0 = *(const bf16x8*)(&Vlds[lcol][c2 * 20 + grp * 4]);
            bf16x8 bV1 = *(const bf16x8*)(&Vlds[16 + lcol][c2 * 20 + grp * 4]);
            oc00 = __builtin_amdgcn_mfma_f32_16x16x32_bf16(aP0, bV0, oc00, 0, 0, 0);
            oc01 = __builtin_amdgcn_mfma_f32_16x16x32_bf16(aP0, bV1, oc01, 0, 0, 0);
            ol0 = __builtin_amdgcn_mfma_f32_16x16x32_bf16(aP0, bOne, ol0, 0, 0, 0);
            oc10 = __builtin_amdgcn_mfma_f32_16x16x32_bf16(aP1, bV0, oc10, 0, 0, 0);
            oc11 = __builtin_amdgcn_mfma_f32_16x16x32_bf16(aP1, bV1, oc11, 0, 0, 0);
            ol1 = __builtin_amdgcn_mfma_f32_16x16x32_bf16(aP1, bOne, ol1, 0, 0, 0);
        }
        __syncthreads();
    }
#pragma unroll
    for (int r = 0; r < 4; ++r) {
        int row0 = qrow0 + grp * 4 + r;
        size_t b0 = ((size_t)row0 * HEADS + head) * KSPLIT + ks;
        PO[b0 * 32 + lcol] = f2bf(oc00[r]);
        PO[b0 * 32 + 16 + lcol] = f2bf(oc01[r]);
        int row1 = row0 + 16;
        size_t b1 = ((size_t)row1 * HEADS + head) * KSPLIT + ks;
        PO[b1 * 32 + lcol] = f2bf(oc10[r]);
        PO[b1 * 32 + 16 + lcol] = f2bf(oc11[r]);
        if (lcol == 0) {
            PM[b0] = msh;
            PL[b0] = ol0[r];
            PM[b1] = msh;
            PL[b1] = ol1[r];
        }
    }
}

__global__ void k_mha_comb(const float* __restrict__ PM, const float* __restrict__ PL,
                           const u16* __restrict__ PO, u16* __restrict__ atthi,
                           u16* __restrict__ attlo) {
    int t = blockIdx.x * 256 + threadIdx.x;
    if (t >= NN * HH) return;
    int row = t >> 7, col = t & 127;
    int head = col >> 5, dim = col & 31;
    size_t b0 = ((size_t)row * HEADS + head) * KSPLIT;
    float m = -INFINITY;
#pragma unroll
    for (int k = 0; k < KSPLIT; ++k) m = fmaxf(m, PM[b0 + k]);
    float l = 0.f, o = 0.f;
#pragma unroll
    for (int k = 0; k < KSPLIT; ++k) {
        float w = __builtin_exp2f(PM[b0 + k] - m);
        l += PL[b0 + k] * w;
        o += bf2f(PO[(b0 + k) * 32 + dim]) * w;
    }
    float v = o / l;
    u16 h = f2bf(v);
    atthi[t] = h;
    attlo[t] = f2bf(v - bf2f(h));
}

// ---------------- output projection ----------------
__global__ __launch_bounds__(64) void k_out(const float* __restrict__ h, const float* __restrict__ w,
                                            const float* __restrict__ b, void* __restrict__ yout,
                                            const int* __restrict__ flag) {
    int n = blockIdx.x, l = threadIdx.x;
    float a0 = 0.f, a1 = 0.f;
    for (int k = l; k < HH; k += 64) {
        float hv = h[(size_t)n * HH + k];
        a0 += hv * w[k];
        a1 += hv * w[HH + k];
    }
#pragma unroll
    for (int off = 32; off > 0; off >>= 1) {
        a0 += __shfl_xor(a0, off);
        a1 += __shfl_xor(a1, off);
    }
    if (l == 0) {
        float o0 = a0 + b[0], o1 = a1 + b[1];
        if (*flag) {
            u16* y = (u16*)yout;
            y[n * 2 + 0] = f2bf(o0);
            y[n * 2 + 1] = f2bf(o1);
        } else {
            float* y = (float*)yout;
            y[n * 2 + 0] = o0;
            y[n * 2 + 1] = o1;
        }
    }
}

extern "C" void kernel_launch(void* const* d_in, const int* in_sizes, int n_in,
                              void* d_out, int out_size, void* d_ws, size_t ws_size,
                              hipStream_t stream) {
    float* W = (float*)d_ws;
    size_t o = 0;
    auto take = [&](size_t n) { size_t r = o; o += n; return r; };
    size_t pb_in = take(HH);
    size_t pattS = take(LL * HEADS * DH);
    size_t pattD = take(LL * HEADS * DH);
    size_t pb_gat = take(LL * HH);
    size_t pb_qkv = take(LL * 3 * HH);
    size_t pb_o  = take(LL * HH);
    size_t pbn_g = take(LL * 3 * HH);
    size_t pbn_b = take(LL * 3 * HH);
    size_t pb1   = take(LL * 2 * HH);
    size_t pb2   = take(LL * HH);
    size_t pw_out = take(2 * HH);
    size_t pb_out = take(2);
    auto takeb = [&](size_t nu16) { size_t r = o; o += (nu16 + 1) / 2; return r; };
    size_t bw_in  = takeb(HH * INF_);
    size_t bw_gat = takeb(LL * HH * HH);
    size_t bw_qkv = takeb(LL * 3 * HH * HH);
    size_t bw_o   = takeb(LL * HH * HH);
    size_t bw1    = takeb(LL * 2 * HH * HH);
    size_t bw2    = takeb(LL * HH * 2 * HH);
    o = (o + 127) & ~(size_t)127;
    size_t ohbuf = take(NH);
    size_t ogat  = take(NH);
    size_t otmp  = take(NH);
    size_t oals  = take(NN * HEADS);
    size_t oald  = take(NN * HEADS);
    size_t opm   = take(NN * HEADS * KSPLIT);
    size_t opl   = take(NN * HEADS * KSPLIT);
    size_t opo   = takeb((size_t)NN * HEADS * KSPLIT * 32);
    size_t oqkvb = takeb(NN * 384);
    size_t oxpb  = takeb(NH);
    size_t oxhi  = takeb(NN * INF_);
    size_t oxlo  = takeb(NN * INF_);
    size_t ohhi  = takeb(NH);
    size_t ohlo  = takeb(NH);
    size_t oahi  = takeb(NH);
    size_t oalo  = takeb(NH);
    size_t oohi  = takeb(NH);
    size_t oolo  = takeb(NH);
    size_t omhi  = takeb(NN * 2 * HH);
    size_t omlo  = takeb(NN * 2 * HH);
    int* ibase    = (int*)(W + o);
    int* iflag    = ibase;
    int* cnt      = ibase + 64;
    int* rowstart = cnt + NN;
    int* cursor   = rowstart + NN;
    int* esrc     = cursor + NN;
    u32* gmax     = (u32*)(esrc + EE);

    float* hbuf = W + ohbuf;
    float* gatb = W + ogat;
    float* tmp  = W + otmp;
    float* als  = W + oals;
    float* ald  = W + oald;
    float* pmb  = W + opm;
    float* plb  = W + opl;
    u16* pob  = (u16*)(W + opo);
    u16* qkvb = (u16*)(W + oqkvb);
    u16* xpb  = (u16*)(W + oxpb);
    u16* xhi = (u16*)(W + oxhi), *xlo = (u16*)(W + oxlo);
    u16* hhi = (u16*)(W + ohhi), *hlo = (u16*)(W + ohlo);
    u16* ahi = (u16*)(W + oahi), *alo = (u16*)(W + oalo);
    u16* ohi = (u16*)(W + oohi), *olo = (u16*)(W + oolo);
    u16* mhi = (u16*)(W + omhi), *mlo = (u16*)(W + omlo);

    const int* src = (const int*)d_in[1];
    const int* dst = (const int*)d_in[1] + EE;
    const u16* dw_in  = (const u16*)d_in[2];
    const u16* dw_gat = (const u16*)d_in[4];
    const u16* dw_qkv = (const u16*)d_in[8];
    const u16* dw_o   = (const u16*)d_in[10];
    const u16* dw1    = (const u16*)d_in[14];
    const u16* dw2    = (const u16*)d_in[16];

    k_detect<<<1, 256, 0, stream>>>((const u16*)d_in[0], iflag, cnt, gmax);

    SegF SF = {};
    int nf = 0;
    auto addf = [&](int idx, size_t off, int n) { SF.src[nf] = d_in[idx]; SF.dst[nf] = (int)off; SF.n[nf] = n; ++nf; };
    addf(3, pb_in, HH);
    addf(5, pattS, LL * HEADS * DH);
    addf(6, pattD, LL * HEADS * DH);
    addf(7, pb_gat, LL * HH);
    addf(9, pb_qkv, LL * 3 * HH);
    addf(11, pb_o, LL * HH);
    addf(12, pbn_g, LL * 3 * HH);
    addf(13, pbn_b, LL * 3 * HH);
    addf(15, pb1, LL * 2 * HH);
    addf(17, pb2, LL * HH);
    addf(18, pw_out, 2 * HH);
    addf(19, pb_out, 2);
    SF.cnt = nf;
    k_cvtf<<<dim3(8, nf), 256, 0, stream>>>(SF, W, iflag);

    SegB SB = {};
    int nb = 0;
    auto addb = [&](int idx, size_t off, int n, u16* d2) {
        SB.src[nb] = d_in[idx]; SB.dst[nb] = (u16*)(W + off); SB.dst2[nb] = d2; SB.n[nb] = n; ++nb;
    };
    addb(2, bw_in, HH * INF_, nullptr);
    addb(4, bw_gat, LL * HH * HH, nullptr);
    addb(8, bw_qkv, LL * 3 * HH * HH, nullptr);
    addb(10, bw_o, LL * HH * HH, nullptr);
    addb(14, bw1, LL * 2 * HH * HH, nullptr);
    addb(16, bw2, LL * HH * 2 * HH, nullptr);
    SB.src[nb] = d_in[0]; SB.dst[nb] = xhi; SB.dst2[nb] = xlo; SB.n[nb] = NN * INF_; ++nb;
    SB.cnt = nb;
    k_cvtb<<<dim3(128, nb), 256, 0, stream>>>(SB, iflag);

    k_hist<<<EE / 256, 256, 0, stream>>>(dst, cnt);
    k_scan<<<1, 256, 0, stream>>>(cnt, rowstart, cursor);
    k_scatter<<<EE / 256, 256, 0, stream>>>(src, dst, cursor, esrc);

    k_mgemm<<<dim3(NN / 32, HH / 64), 128, 0, stream>>>(xhi, xlo, (u16*)(W + bw_in), dw_in, iflag,
                                                        W + pb_in, hbuf, nullptr, hhi, hlo, INF_, HH, 1);

    for (int l = 0; l < LL; ++l) {
        k_gemm_gq<<<dim3(NN / 32, 8), 128, 0, stream>>>(hhi, hlo,
                                                        (u16*)(W + bw_gat) + (size_t)l * HH * HH,
                                                        dw_gat + (size_t)l * HH * HH,
                                                        (u16*)(W + bw_qkv) + (size_t)l * 3 * HH * HH,
                                                        dw_qkv + (size_t)l * 3 * HH * HH,
                                                        iflag, W + pb_qkv + l * 3 * HH, xpb, qkvb);
        k_attlog<<<(NN * HEADS) / 256, 256, 0, stream>>>(xpb, W + pattS + l * HEADS * DH,
                                                         W + pattD + l * HEADS * DH, als, ald,
                                                         gmax + l * 8);
        k_gat_node<<<NN, 128, 0, stream>>>(esrc, rowstart, cnt, als, ald, xpb, gatb, gmax + l * 8);
        k_mha_split<<<(NN / 128) * HEADS * KSPLIT, 256, 0, stream>>>(qkvb, pmb, plb, pob);
        k_mha_comb<<<(NN * HH) / 256, 256, 0, stream>>>(pmb, plb, pob, ahi, alo);
        k_gemm_wo<<<dim3(NN / 32, HH / 64), 128, 0, stream>>>(ahi, alo,
                                                              (u16*)(W + bw_o) + (size_t)l * HH * HH,
                                                              dw_o + (size_t)l * HH * HH, iflag,
                                                              W + pb_o + l * HH, gatb, hbuf,
                                                              W + pb_gat + l * HH, W + pbn_g + l * 3 * HH,
                                                              W + pbn_b + l * 3 * HH, tmp, ohi, olo);
        k_mgemm<<<dim3(NN / 32, 256 / 64), 128, 0, stream>>>(ohi, olo,
                                                             (u16*)(W + bw1) + (size_t)l * 2 * HH * HH,
                                                             dw1 + (size_t)l * 2 * HH * HH, iflag,
                                                             W + pb1 + l * 2 * HH, nullptr, nullptr,
                                                             mhi, mlo, HH, 2 * HH, 1);
        k_gemm_w2<<<dim3(NN / 32, HH / 64), 128, 0, stream>>>(mhi, mlo,
                                                              (u16*)(W + bw2) + (size_t)l * HH * 2 * HH,
                                                              dw2 + (size_t)l * HH * 2 * HH, iflag,
                                                              W + pb2 + l * HH, tmp,
                                                              W + pbn_g + l * 3 * HH + 2 * HH,
                                                              W + pbn_b + l * 3 * HH + 2 * HH,
                                                              hbuf, hhi, hlo);
    }
    k_out<<<NN, 64, 0, stream>>>(hbuf, W + pw_out, W + pb_out, d_out, iflag);
}